// Round 12
// baseline (222.572 us; speedup 1.0000x reference)
//
#include <hip/hip_runtime.h>
#include <cmath>

// LinearAttention round 12.
// vs r11: gemm16w epilogue rewritten — acc goes through a swizzled LDS tile
// (reusing the dead staging buffers) and drains as 256B/512B contiguous row
// bursts. r11's scattered 2B/4B strided stores capped HBM write BW at 2.8 TB/s;
// this is the attn5-proven store pattern.

#define B 4
#define C 256
#define Hh 128
#define Wd 128
#define HW (Hh*Wd)
#define HEADS 8
#define HD 32
#define OSCALE 256.0f
#define NSP 16

typedef _Float16 half_t;
typedef _Float16 f16x8 __attribute__((ext_vector_type(8)));
typedef float f32x4 __attribute__((ext_vector_type(4)));

__device__ __forceinline__ void gload_lds16(const half_t* g, half_t* l) {
  __builtin_amdgcn_global_load_lds((const __attribute__((address_space(1))) void*)g,
                                   (__attribute__((address_space(3))) void*)l, 16, 0, 0);
}

// ---------------- all weights fp32 -> fp16, one launch ----------------
__global__ __launch_bounds__(256) void wcvt_all(const float* __restrict__ wq1,
                                                const float* __restrict__ wk1,
                                                const float* __restrict__ wv1,
                                                const float* __restrict__ wout,
                                                half_t* __restrict__ Wh,
                                                half_t* __restrict__ Woh) {
  int i = blockIdx.x * 256 + threadIdx.x;  // grid 1024 -> 262144
  if (i < 65536) Wh[i] = (half_t)wq1[i];
  else if (i < 131072) Wh[i] = (half_t)wk1[i - 65536];
  else if (i < 196608) Wh[i] = (half_t)wv1[i - 131072];
  else Woh[i - 196608] = (half_t)wout[i - 196608];
}

// ---------------- channel LayerNorm -> X_h[b][pix][c] fp16 ----------------
__global__ __launch_bounds__(256) void ln2(const float* __restrict__ fmap,
                                           const float* __restrict__ g,
                                           half_t* __restrict__ Xh) {
  int b = blockIdx.y;
  int lane = threadIdx.x & 63;
  int gq = threadIdx.x >> 6;               // 0..3 channel group
  int px = blockIdx.x * 64 + lane;
  __shared__ float gs[C];
  __shared__ float sm1[4][64], sm2[4][64];
  gs[threadIdx.x] = g[threadIdx.x];
  const float* fp = fmap + ((size_t)b * C + gq * 64) * HW + px;
  float vbuf[64];
  float s = 0.f, s2 = 0.f;
#pragma unroll
  for (int j = 0; j < 64; ++j) {
    float v = fp[(size_t)j * HW];
    vbuf[j] = v;
    s += v; s2 = fmaf(v, v, s2);
  }
  sm1[gq][lane] = s; sm2[gq][lane] = s2;
  __syncthreads();
  float st = 0.f, st2 = 0.f;
#pragma unroll
  for (int q = 0; q < 4; ++q) { st += sm1[q][lane]; st2 += sm2[q][lane]; }
  float mean = st * (1.f / C);
  float var = st2 * (1.f / C) - mean * mean;
  float rstd = rsqrtf(var + 1e-5f);
  half_t* xp = Xh + ((size_t)b * HW + px) * 256 + gq * 64;
#pragma unroll
  for (int j0 = 0; j0 < 64; j0 += 8) {
    f16x8 v8;
#pragma unroll
    for (int jj = 0; jj < 8; ++jj)
      v8[jj] = (half_t)((vbuf[j0 + jj] - mean) * rstd * gs[gq * 64 + j0 + jj]);
    *(f16x8*)(xp + j0) = v8;
  }
}

// ---------------- fp16 MFMA GEMM, 512 threads, LDS-tile epilogue ----------------
// Y[m][pix] = sum_c W[m][c] X[pix][c]. Tile 128m x 128px, BK=64, 8 waves (4m x 2px).
template<int MODE>
__global__ __launch_bounds__(512) void gemm16w(const half_t* __restrict__ Xh,
                                               const half_t* __restrict__ Wh,
                                               half_t* __restrict__ Yh,
                                               float* __restrict__ Yf) {
  __shared__ __align__(16) char smem[65536];       // staging (2x16KB X + 2x16KB W) / out tile
  half_t* Xs0 = (half_t*)smem;
  half_t* Xs1 = (half_t*)(smem + 16384);
  half_t* Ws0 = (half_t*)(smem + 32768);
  half_t* Ws1 = (half_t*)(smem + 49152);
  const int tid = threadIdx.x;
  const int wave = tid >> 6, lane = tid & 63;
  const int lr = lane & 15, lq = lane >> 4;
  const int b = blockIdx.z;
  const int pix0 = blockIdx.x * 128;
  const int m0 = blockIdx.y * 128;
  const int wm = wave >> 1, wn = wave & 1;   // 4 m-waves x 2 px-waves

  const half_t* xb = Xh + ((size_t)b * HW + pix0) * 256;
  const half_t* wb = Wh + (size_t)m0 * 256;

  f32x4 acc[2][4];
#pragma unroll
  for (int i = 0; i < 2; ++i)
#pragma unroll
    for (int j = 0; j < 4; ++j) { f32x4 z = {0.f, 0.f, 0.f, 0.f}; acc[i][j] = z; }

  // stage K-chunk 0 into buf 0 (async, drained by __syncthreads)
#pragma unroll
  for (int it = 0; it < 2; ++it) {
    int e = it * 512 + tid, r = e >> 3, c = e & 7;   // 1024 chunks = 128 rows x 8
    int go = (c ^ (r & 7)) << 3;                     // inverse-swizzled SOURCE
    gload_lds16(xb + (size_t)r * 256 + go, Xs0 + e * 8);
    gload_lds16(wb + (size_t)r * 256 + go, Ws0 + e * 8);
  }
  __syncthreads();

#pragma unroll
  for (int kk = 0; kk < 4; ++kk) {
    half_t* Xsb = (kk & 1) ? Xs1 : Xs0;
    half_t* Wsb = (kk & 1) ? Ws1 : Ws0;
    if (kk < 3) {  // async-stage next chunk into other buffer before compute
      half_t* Xsn = (kk & 1) ? Xs0 : Xs1;
      half_t* Wsn = (kk & 1) ? Ws0 : Ws1;
#pragma unroll
      for (int it = 0; it < 2; ++it) {
        int e = it * 512 + tid, r = e >> 3, c = e & 7;
        int go = (kk + 1) * 64 + ((c ^ (r & 7)) << 3);
        gload_lds16(xb + (size_t)r * 256 + go, Xsn + e * 8);
        gload_lds16(wb + (size_t)r * 256 + go, Wsn + e * 8);
      }
    }
#pragma unroll
    for (int kf = 0; kf < 2; ++kf) {
      f16x8 afr[2], bfr[4];
#pragma unroll
      for (int mf = 0; mf < 2; ++mf) {
        int r = wm * 32 + mf * 16 + lr;
        int q = kf * 4 + lq;
        afr[mf] = *(const f16x8*)&Wsb[r * 64 + ((q ^ (r & 7)) << 3)];  // swz READ
      }
#pragma unroll
      for (int nf = 0; nf < 4; ++nf) {
        int r = wn * 64 + nf * 16 + lr;
        int q = kf * 4 + lq;
        bfr[nf] = *(const f16x8*)&Xsb[r * 64 + ((q ^ (r & 7)) << 3)];
      }
#pragma unroll
      for (int mf = 0; mf < 2; ++mf)
#pragma unroll
        for (int nf = 0; nf < 4; ++nf)
          acc[mf][nf] = __builtin_amdgcn_mfma_f32_16x16x32_f16(afr[mf], bfr[nf], acc[mf][nf], 0, 0, 0);
    }
    __syncthreads();  // drains vmcnt + lgkm; after kk=3 this frees LDS for the out tile
  }

  // ---- epilogue via swizzled LDS tile -> contiguous row bursts ----
  if constexpr (MODE == 0) {
    // fp16 tile [128 m][128 px], row stride 256B, 16B-chunk XOR (row&7)
#pragma unroll
    for (int mf = 0; mf < 2; ++mf)
#pragma unroll
      for (int nf = 0; nf < 4; ++nf)
#pragma unroll
        for (int j = 0; j < 4; ++j) {
          int row = wm * 32 + mf * 16 + lq * 4 + j;
          int col = wn * 64 + nf * 16 + lr;
          int byte = row * 256 + ((col * 2) ^ ((row & 7) << 4));
          *(half_t*)(smem + byte) = (half_t)acc[mf][nf][j];
        }
    __syncthreads();
    half_t* dst_base = Yh + (size_t)(m0 >> 8) * ((size_t)B * C * HW)
                       + ((size_t)(b * C + (m0 & 255))) * HW + pix0;
#pragma unroll
    for (int it = 0; it < 4; ++it) {
      int i = it * 512 + tid;                 // 2048 chunks = 128 rows x 16
      int row = i >> 4, ch = i & 15;
      int src = row * 256 + ((ch * 16) ^ ((row & 7) << 4));
      *(f16x8*)(dst_base + (size_t)row * HW + ch * 8) = *(const f16x8*)(smem + src);
    }
  } else {
    // fp32 tile [128 m][128 px], row stride 512B, 16B-chunk XOR (row&7)
#pragma unroll
    for (int mf = 0; mf < 2; ++mf)
#pragma unroll
      for (int nf = 0; nf < 4; ++nf)
#pragma unroll
        for (int j = 0; j < 4; ++j) {
          int row = wm * 32 + mf * 16 + lq * 4 + j;
          int col = wn * 64 + nf * 16 + lr;
          int byte = row * 512 + ((col * 4) ^ ((row & 7) << 4));
          *(float*)(smem + byte) = acc[mf][nf][j] * (1.0f / OSCALE);
        }
    __syncthreads();
    float* dst_base = Yf + ((size_t)(b * C + m0)) * HW + pix0;
#pragma unroll
    for (int it = 0; it < 8; ++it) {
      int i = it * 512 + tid;                 // 4096 chunks = 128 rows x 32
      int row = i >> 5, ch = i & 31;
      int src = row * 512 + ((ch * 16) ^ ((row & 7) << 4));
      *(float4*)(dst_base + (size_t)row * HW + ch * 4) = *(const float4*)(smem + src);
    }
  }
}

// ---------------- vectorized depthwise 3x3, SAME pad ----------------
// MODE 0: fp32 out; MODE 1: fp16 out; MODE 2: fp16 exp(out) (K path).
template<int MODE>
__global__ __launch_bounds__(256) void dw3x3_v(const half_t* __restrict__ Yin,
                                               const float* __restrict__ W2,
                                               void* __restrict__ Zv) {
  int c = blockIdx.y, b = blockIdx.z;
  int r = threadIdx.x >> 4;
  int j0 = (threadIdx.x & 15) * 8;
  int i = blockIdx.x * 16 + r;
  const half_t* plane = Yin + ((size_t)(b * C + c)) * HW;
  float w[9];
#pragma unroll
  for (int k = 0; k < 9; ++k) w[k] = W2[c * 9 + k];
  float acc[8];
#pragma unroll
  for (int p = 0; p < 8; ++p) acc[p] = 0.f;
#pragma unroll
  for (int dr = 0; dr < 3; ++dr) {
    int ii = i + dr - 1;
    if (ii < 0 || ii >= Hh) continue;
    const half_t* rp = plane + ii * Wd + j0;
    f16x8 cv = *(const f16x8*)rp;
    float lv = (j0 > 0) ? (float)rp[-1] : 0.f;
    float rv = (j0 + 8 < Wd) ? (float)rp[8] : 0.f;
    float cf[8];
#pragma unroll
    for (int p = 0; p < 8; ++p) cf[p] = (float)cv[p];
    float w0 = w[dr * 3], w1 = w[dr * 3 + 1], w2v = w[dr * 3 + 2];
#pragma unroll
    for (int p = 0; p < 8; ++p) {
      float l = (p == 0) ? lv : cf[p - 1];
      float rr = (p == 7) ? rv : cf[p + 1];
      acc[p] = fmaf(w0, l, acc[p]);
      acc[p] = fmaf(w1, cf[p], acc[p]);
      acc[p] = fmaf(w2v, rr, acc[p]);
    }
  }
  size_t off = ((size_t)(b * C + c)) * HW + i * Wd + j0;
  if constexpr (MODE == 1 || MODE == 2) {
    f16x8 o8;
#pragma unroll
    for (int p = 0; p < 8; ++p)
      o8[p] = (half_t)(MODE == 2 ? expf(acc[p]) : acc[p]);
    *(f16x8*)((half_t*)Zv + off) = o8;
  } else {
    float* op = (float*)Zv + off;
    *(float4*)op = make_float4(acc[0], acc[1], acc[2], acc[3]);
    *(float4*)(op + 4) = make_float4(acc[4], acc[5], acc[6], acc[7]);
  }
}

// ---------------- sum of ek per (b,c) row -> Sk ----------------
__global__ __launch_bounds__(256) void ksum(const half_t* __restrict__ EK,
                                            float* __restrict__ Sk) {
  int c = blockIdx.x, b = blockIdx.y;
  const half_t* p = EK + ((size_t)(b * C + c)) * HW;
  int t = threadIdx.x;
  float s = 0.f;
  for (int i = t * 8; i < HW; i += 2048) {
    f16x8 v = *(const f16x8*)(p + i);
#pragma unroll
    for (int j = 0; j < 8; ++j) s += (float)v[j];
  }
  __shared__ float red[256];
  red[t] = s; __syncthreads();
  for (int st = 128; st > 0; st >>= 1) {
    if (t < st) red[t] += red[t + st];
    __syncthreads();
  }
  if (t == 0) Sk[b * C + c] = red[0];
}

// ---------------- ctx_raw = EK @ V^T per head, pure MFMA ----------------
__global__ __launch_bounds__(256) void ctx_mfma(const half_t* __restrict__ EK,
                                                const half_t* __restrict__ V,
                                                float* __restrict__ part) {
  int bh = blockIdx.x, sp = blockIdx.y;
  int wave = threadIdx.x >> 6, lane = threadIdx.x & 63;
  int lr = lane & 15, lq = lane >> 4;
  const size_t base = (size_t)bh * HD * HW;
  const half_t* ekp = EK + base + (size_t)lr * HW;
  const half_t* vp  = V  + base + (size_t)lr * HW;
  f32x4 a00 = {0.f,0.f,0.f,0.f}, a01 = a00, a10 = a00, a11 = a00;
  const int n0w = sp * 1024 + wave * 256 + lq * 8;
#pragma unroll
  for (int ks = 0; ks < 8; ++ks) {
    int n = n0w + ks * 32;
    f16x8 fa0 = *(const f16x8*)(ekp + n);
    f16x8 fa1 = *(const f16x8*)(ekp + (size_t)16 * HW + n);
    f16x8 fb0 = *(const f16x8*)(vp + n);
    f16x8 fb1 = *(const f16x8*)(vp + (size_t)16 * HW + n);
    a00 = __builtin_amdgcn_mfma_f32_16x16x32_f16(fa0, fb0, a00, 0, 0, 0);
    a01 = __builtin_amdgcn_mfma_f32_16x16x32_f16(fa0, fb1, a01, 0, 0, 0);
    a10 = __builtin_amdgcn_mfma_f32_16x16x32_f16(fa1, fb0, a10, 0, 0, 0);
    a11 = __builtin_amdgcn_mfma_f32_16x16x32_f16(fa1, fb1, a11, 0, 0, 0);
  }
  __shared__ float red[4][1024];
#pragma unroll
  for (int j = 0; j < 4; ++j) {
    int dlo = lq * 4 + j;
    red[wave][(dlo)      * 32 + lr]      = a00[j];
    red[wave][(dlo)      * 32 + 16 + lr] = a01[j];
    red[wave][(dlo + 16) * 32 + lr]      = a10[j];
    red[wave][(dlo + 16) * 32 + 16 + lr] = a11[j];
  }
  __syncthreads();
  float* pp = part + ((size_t)sp * 32 + bh) * 1024;
  for (int idx = threadIdx.x; idx < 1024; idx += 256)
    pp[idx] = red[0][idx] + red[1][idx] + red[2][idx] + red[3][idx];
}

// ---------------- reduce ctx partials, apply 1/S, emit fp16 TRANSPOSED [e][d] ----------------
__global__ __launch_bounds__(256) void ctxred(const float* __restrict__ part,
                                              const float* __restrict__ Sk,
                                              half_t* __restrict__ ctxh) {
  int bh = blockIdx.x;
  int t = threadIdx.x;
  for (int idx = t; idx < 1024; idx += 256) {
    int d = idx >> 5, e = idx & 31;
    float s = 0.f;
#pragma unroll
    for (int sp = 0; sp < NSP; ++sp) s += part[((size_t)sp * 32 + bh) * 1024 + idx];
    ctxh[(size_t)bh * 1024 + e * 32 + d] = (half_t)(s / Sk[bh * HD + d]);
  }
}

// ---------------- attn5: P@ctx via MFMA; SiLU; swizzled LDS -> coalesced stores ----------------
__global__ __launch_bounds__(256) void attn5(const half_t* __restrict__ Qh,
                                             const half_t* __restrict__ ctxh,
                                             half_t* __restrict__ Oh) {
  const int b = blockIdx.y;
  const int lane = threadIdx.x & 63;
  const int w = threadIdx.x >> 6;
  const int lr = lane & 15, lq = lane >> 4;
  const int px = blockIdx.x * 64 + w * 16 + lr;       // A-row pixel for this lane
  __shared__ half_t osm[64 * 256];                    // 32KB output tile [px][c] swizzled

  f16x8 cf[HEADS][2];
#pragma unroll
  for (int h = 0; h < HEADS; ++h)
#pragma unroll
    for (int eh = 0; eh < 2; ++eh)
      cf[h][eh] = *(const f16x8*)(ctxh + ((size_t)(b * HEADS + h)) * 1024
                                  + (eh * 16 + lr) * 32 + lq * 8);

  const int pxl_base = w * 16 + lq * 4;               // D-row local pixel base
#pragma unroll
  for (int h = 0; h < HEADS; ++h) {
    const half_t* qp = Qh + ((size_t)(b * C + h * HD + lq * 8)) * HW + px;
    float ev[8];
    float psum = 0.f;
#pragma unroll
    for (int j = 0; j < 8; ++j) {
      ev[j] = expf((float)qp[(size_t)j * HW]);        // no max pass: logits bounded
      psum += ev[j];
    }
    float s = psum;
    s += __shfl_xor(s, 16, 64);
    s += __shfl_xor(s, 32, 64);                       // sum over 4 lq groups (fixed lr)
    float inv = 0.1767766952966369f / s;              // 32^-0.5 / s
    f16x8 pa;
#pragma unroll
    for (int j = 0; j < 8; ++j) pa[j] = (half_t)(ev[j] * inv);

    f32x4 z = {0.f, 0.f, 0.f, 0.f};
    f32x4 a0 = __builtin_amdgcn_mfma_f32_16x16x32_f16(pa, cf[h][0], z, 0, 0, 0);
    f32x4 a1 = __builtin_amdgcn_mfma_f32_16x16x32_f16(pa, cf[h][1], z, 0, 0, 0);

#pragma unroll
    for (int eh = 0; eh < 2; ++eh) {
      f32x4 a = eh ? a1 : a0;
      int c = h * 32 + eh * 16 + lr;
#pragma unroll
      for (int j = 0; j < 4; ++j) {
        int pxl = pxl_base + j;                       // D row = lq*4+j
        float v = a[j];
        float sg = 1.f / (1.f + expf(-v));
        int byte = pxl * 512 + ((c * 2) ^ (((pxl >> 2) & 7) << 4));
        *(half_t*)((char*)osm + byte) = (half_t)(v * sg * OSCALE);
      }
    }
  }
  __syncthreads();

  half_t* ob = Oh + ((size_t)b * HW + blockIdx.x * 64) * 256;
#pragma unroll
  for (int it = 0; it < 8; ++it) {
    int i = it * 256 + threadIdx.x;                   // 16B-chunk index, 2048 total
    int pxl = i >> 5;
    int inrow = (i & 31) * 16;
    int src = pxl * 512 + (inrow ^ (((pxl >> 2) & 7) << 4));
    *(f16x8*)(ob + (size_t)pxl * 256 + inrow / 2) = *(const f16x8*)((const char*)osm + src);
  }
}

extern "C" void kernel_launch(void* const* d_in, const int* in_sizes, int n_in,
                              void* d_out, int out_size, void* d_ws, size_t ws_size,
                              hipStream_t stream) {
  const float* fmap = (const float*)d_in[0];
  const float* g    = (const float*)d_in[1];
  const float* wq1  = (const float*)d_in[2];
  const float* wq2  = (const float*)d_in[3];
  const float* wk1  = (const float*)d_in[4];
  const float* wk2  = (const float*)d_in[5];
  const float* wv1  = (const float*)d_in[6];
  const float* wv2  = (const float*)d_in[7];
  const float* wout = (const float*)d_in[8];
  float* out = (float*)d_out;
  char* ws = (char*)d_ws;

  const size_t SZ = (size_t)B * C * HW;
  const size_t Mi = (size_t)1 << 20;
  // layout (byte offsets), live ranges audited:
  half_t* Xh   = (half_t*)(ws);                  // [0,32Mi)    ln2 -> gemm<0>
  half_t* Yh   = (half_t*)(ws + 32 * Mi);        // [32,128Mi)  Yq|Yk|Yv fp16
  half_t* Qh   = (half_t*)(ws + 128 * Mi);       // [128,160Mi) dwQ -> attn5
  half_t* EK   = (half_t*)(ws);                  // [0,32Mi)    exp(k) fp16 (Xh dead)
  half_t* Vh   = (half_t*)out;                   // d_out as fp16 V until ctx_mfma done
  float*  part = (float*)(ws + 96 * Mi);         // [96,98Mi)   over dead Yv
  float*  Sk   = (float*)(ws + 99 * Mi);         // 4KB
  half_t* ctxh = (half_t*)(ws + 100 * Mi);       // 64KB fp16 transposed [bh][e][d]
  half_t* Wh   = (half_t*)(ws + 192 * Mi);
  half_t* Woh  = (half_t*)(ws + 192 * Mi + 512 * 1024);
  half_t* Oh   = (half_t*)(ws + 32 * Mi);        // over dead Yq

  wcvt_all<<<dim3(1024), 256, 0, stream>>>(wq1, wk1, wv1, wout, Wh, Woh);

  ln2<<<dim3(HW / 64, B), 256, 0, stream>>>(fmap, g, Xh);

  gemm16w<0><<<dim3(HW / 128, 6, B), 512, 0, stream>>>(Xh, Wh, Yh, nullptr);

  dw3x3_v<1><<<dim3(Hh / 16, C, B), 256, 0, stream>>>(Yh, wq2, Qh);            // Q fp16
  dw3x3_v<2><<<dim3(Hh / 16, C, B), 256, 0, stream>>>(Yh + SZ, wk2, EK);       // exp(K) fp16
  dw3x3_v<1><<<dim3(Hh / 16, C, B), 256, 0, stream>>>(Yh + 2 * SZ, wv2, Vh);   // V fp16

  ksum<<<dim3(C, B), 256, 0, stream>>>(EK, Sk);

  ctx_mfma<<<dim3(HEADS * B, NSP), 256, 0, stream>>>(EK, Vh, part);
  ctxred<<<dim3(32), 256, 0, stream>>>(part, Sk, ctxh);

  attn5<<<dim3(HW / 64, B), 256, 0, stream>>>(Qh, ctxh, Oh);

  gemm16w<1><<<dim3(HW / 128, 2, B), 512, 0, stream>>>(Oh, Woh, nullptr, out);
}

// Round 13
// 221.434 us; speedup vs baseline: 1.0051x; 1.0051x over previous
//
#include <hip/hip_runtime.h>
#include <cmath>

// LinearAttention round 13.
// vs r12: gemm16p — BK=32, 4-slot LDS ring (64KB total), prefetch depth 2,
// counted s_waitcnt vmcnt(4/2/0) + single raw s_barrier per K-step (8 steps).
// Loads stay in flight ~2 iterations instead of draining at every barrier.
// Grid swapped (x = m-block) so the 6 m-blocks sharing an X panel are
// consecutive -> same XCD L2.

#define B 4
#define C 256
#define Hh 128
#define Wd 128
#define HW (Hh*Wd)
#define HEADS 8
#define HD 32
#define OSCALE 256.0f
#define NSP 16

typedef _Float16 half_t;
typedef _Float16 f16x8 __attribute__((ext_vector_type(8)));
typedef float f32x4 __attribute__((ext_vector_type(4)));

__device__ __forceinline__ void gload_lds16(const half_t* g, half_t* l) {
  __builtin_amdgcn_global_load_lds((const __attribute__((address_space(1))) void*)g,
                                   (__attribute__((address_space(3))) void*)l, 16, 0, 0);
}

// ---------------- all weights fp32 -> fp16, one launch ----------------
__global__ __launch_bounds__(256) void wcvt_all(const float* __restrict__ wq1,
                                                const float* __restrict__ wk1,
                                                const float* __restrict__ wv1,
                                                const float* __restrict__ wout,
                                                half_t* __restrict__ Wh,
                                                half_t* __restrict__ Woh) {
  int i = blockIdx.x * 256 + threadIdx.x;  // grid 1024 -> 262144
  if (i < 65536) Wh[i] = (half_t)wq1[i];
  else if (i < 131072) Wh[i] = (half_t)wk1[i - 65536];
  else if (i < 196608) Wh[i] = (half_t)wv1[i - 131072];
  else Woh[i - 196608] = (half_t)wout[i - 196608];
}

// ---------------- channel LayerNorm -> X_h[b][pix][c] fp16 ----------------
__global__ __launch_bounds__(256) void ln2(const float* __restrict__ fmap,
                                           const float* __restrict__ g,
                                           half_t* __restrict__ Xh) {
  int b = blockIdx.y;
  int lane = threadIdx.x & 63;
  int gq = threadIdx.x >> 6;               // 0..3 channel group
  int px = blockIdx.x * 64 + lane;
  __shared__ float gs[C];
  __shared__ float sm1[4][64], sm2[4][64];
  gs[threadIdx.x] = g[threadIdx.x];
  const float* fp = fmap + ((size_t)b * C + gq * 64) * HW + px;
  float vbuf[64];
  float s = 0.f, s2 = 0.f;
#pragma unroll
  for (int j = 0; j < 64; ++j) {
    float v = fp[(size_t)j * HW];
    vbuf[j] = v;
    s += v; s2 = fmaf(v, v, s2);
  }
  sm1[gq][lane] = s; sm2[gq][lane] = s2;
  __syncthreads();
  float st = 0.f, st2 = 0.f;
#pragma unroll
  for (int q = 0; q < 4; ++q) { st += sm1[q][lane]; st2 += sm2[q][lane]; }
  float mean = st * (1.f / C);
  float var = st2 * (1.f / C) - mean * mean;
  float rstd = rsqrtf(var + 1e-5f);
  half_t* xp = Xh + ((size_t)b * HW + px) * 256 + gq * 64;
#pragma unroll
  for (int j0 = 0; j0 < 64; j0 += 8) {
    f16x8 v8;
#pragma unroll
    for (int jj = 0; jj < 8; ++jj)
      v8[jj] = (half_t)((vbuf[j0 + jj] - mean) * rstd * gs[gq * 64 + j0 + jj]);
    *(f16x8*)(xp + j0) = v8;
  }
}

// ---------------- fp16 MFMA GEMM: BK=32 ring-4, counted vmcnt, 1 barrier/step ----------------
// Y[m][pix] = sum_c W[m][c] X[pix][c]. Tile 128m x 128px, 8 waves (4m x 2px).
// Ring slot s (16KB): X[128rows][4 chunks of 16B] then W at +8192.
// Chunk XOR swizzle: lds_chunk = g_chunk ^ ((row>>1)&3)  (2-way on ds_read = free).
template<int MODE>
__global__ __launch_bounds__(512) void gemm16p(const half_t* __restrict__ Xh,
                                               const half_t* __restrict__ Wh,
                                               half_t* __restrict__ Yh,
                                               float* __restrict__ Yf) {
  __shared__ __align__(16) char smem[65536];       // 4 ring slots / out tile
  const int tid = threadIdx.x;
  const int wave = tid >> 6, lane = tid & 63;
  const int lr = lane & 15, lq = lane >> 4;
  const int b = blockIdx.z;
  const int m0 = blockIdx.x * 128;                 // x = m-block (L2 locality)
  const int pix0 = blockIdx.y * 128;
  const int wm = wave >> 1, wn = wave & 1;         // 4 m-waves x 2 px-waves

  const half_t* xb = Xh + ((size_t)b * HW + pix0) * 256;
  const half_t* wb = Wh + (size_t)m0 * 256;

  f32x4 acc[2][4];
#pragma unroll
  for (int i = 0; i < 2; ++i)
#pragma unroll
    for (int j = 0; j < 4; ++j) { f32x4 z = {0.f, 0.f, 0.f, 0.f}; acc[i][j] = z; }

#define STAGE(kt, s) do {                                                       \
    int r_ = tid >> 2, c_ = tid & 3;                                            \
    int cs_ = c_ ^ ((r_ >> 1) & 3);                                             \
    gload_lds16(xb + (size_t)r_ * 256 + (kt) * 32 + (cs_ << 3),                 \
                (half_t*)(smem + (s) * 16384) + tid * 8);                       \
    gload_lds16(wb + (size_t)r_ * 256 + (kt) * 32 + (cs_ << 3),                 \
                (half_t*)(smem + (s) * 16384 + 8192) + tid * 8);                \
  } while (0)

  STAGE(0, 0);                                     // 2 loads/thread in flight
  STAGE(1, 1);                                     // 4

#pragma unroll
  for (int t = 0; t < 8; ++t) {
    if (t < 6) STAGE(t + 2, (t + 2) & 3);          // 6 in flight
    if (t < 6)       asm volatile("s_waitcnt vmcnt(4)" ::: "memory");
    else if (t == 6) asm volatile("s_waitcnt vmcnt(2)" ::: "memory");
    else             asm volatile("s_waitcnt vmcnt(0)" ::: "memory");
    __builtin_amdgcn_sched_barrier(0);
    __builtin_amdgcn_s_barrier();                  // all waves: tile t landed
    const char* slot = smem + (t & 3) * 16384;
    f16x8 afr[2], bfr[4];
#pragma unroll
    for (int mf = 0; mf < 2; ++mf) {
      int r = wm * 32 + mf * 16 + lr;
      afr[mf] = *(const f16x8*)(slot + 8192 + r * 64 + ((lq ^ ((r >> 1) & 3)) << 4));
    }
#pragma unroll
    for (int nf = 0; nf < 4; ++nf) {
      int r = wn * 64 + nf * 16 + lr;
      bfr[nf] = *(const f16x8*)(slot + r * 64 + ((lq ^ ((r >> 1) & 3)) << 4));
    }
#pragma unroll
    for (int mf = 0; mf < 2; ++mf)
#pragma unroll
      for (int nf = 0; nf < 4; ++nf)
        acc[mf][nf] = __builtin_amdgcn_mfma_f32_16x16x32_f16(afr[mf], bfr[nf], acc[mf][nf], 0, 0, 0);
  }
#undef STAGE
  asm volatile("s_waitcnt lgkmcnt(0)" ::: "memory");
  __builtin_amdgcn_sched_barrier(0);
  __builtin_amdgcn_s_barrier();                    // smem free for out tile

  // ---- epilogue via swizzled LDS tile -> contiguous row bursts ----
  if constexpr (MODE == 0) {
#pragma unroll
    for (int mf = 0; mf < 2; ++mf)
#pragma unroll
      for (int nf = 0; nf < 4; ++nf)
#pragma unroll
        for (int j = 0; j < 4; ++j) {
          int row = wm * 32 + mf * 16 + lq * 4 + j;
          int col = wn * 64 + nf * 16 + lr;
          int byte = row * 256 + ((col * 2) ^ ((row & 7) << 4));
          *(half_t*)(smem + byte) = (half_t)acc[mf][nf][j];
        }
    __syncthreads();
    half_t* dst_base = Yh + (size_t)(m0 >> 8) * ((size_t)B * C * HW)
                       + ((size_t)(b * C + (m0 & 255))) * HW + pix0;
#pragma unroll
    for (int it = 0; it < 4; ++it) {
      int i = it * 512 + tid;                 // 2048 chunks = 128 rows x 16
      int row = i >> 4, ch = i & 15;
      int src = row * 256 + ((ch * 16) ^ ((row & 7) << 4));
      *(f16x8*)(dst_base + (size_t)row * HW + ch * 8) = *(const f16x8*)(smem + src);
    }
  } else {
#pragma unroll
    for (int mf = 0; mf < 2; ++mf)
#pragma unroll
      for (int nf = 0; nf < 4; ++nf)
#pragma unroll
        for (int j = 0; j < 4; ++j) {
          int row = wm * 32 + mf * 16 + lq * 4 + j;
          int col = wn * 64 + nf * 16 + lr;
          int byte = row * 512 + ((col * 4) ^ ((row & 7) << 4));
          *(float*)(smem + byte) = acc[mf][nf][j] * (1.0f / OSCALE);
        }
    __syncthreads();
    float* dst_base = Yf + ((size_t)(b * C + m0)) * HW + pix0;
#pragma unroll
    for (int it = 0; it < 8; ++it) {
      int i = it * 512 + tid;                 // 4096 chunks = 128 rows x 32
      int row = i >> 5, ch = i & 31;
      int src = row * 512 + ((ch * 16) ^ ((row & 7) << 4));
      *(float4*)(dst_base + (size_t)row * HW + ch * 4) = *(const float4*)(smem + src);
    }
  }
}

// ---------------- vectorized depthwise 3x3, SAME pad ----------------
// MODE 0: fp32 out; MODE 1: fp16 out; MODE 2: fp16 exp(out) (K path).
template<int MODE>
__global__ __launch_bounds__(256) void dw3x3_v(const half_t* __restrict__ Yin,
                                               const float* __restrict__ W2,
                                               void* __restrict__ Zv) {
  int c = blockIdx.y, b = blockIdx.z;
  int r = threadIdx.x >> 4;
  int j0 = (threadIdx.x & 15) * 8;
  int i = blockIdx.x * 16 + r;
  const half_t* plane = Yin + ((size_t)(b * C + c)) * HW;
  float w[9];
#pragma unroll
  for (int k = 0; k < 9; ++k) w[k] = W2[c * 9 + k];
  float acc[8];
#pragma unroll
  for (int p = 0; p < 8; ++p) acc[p] = 0.f;
#pragma unroll
  for (int dr = 0; dr < 3; ++dr) {
    int ii = i + dr - 1;
    if (ii < 0 || ii >= Hh) continue;
    const half_t* rp = plane + ii * Wd + j0;
    f16x8 cv = *(const f16x8*)rp;
    float lv = (j0 > 0) ? (float)rp[-1] : 0.f;
    float rv = (j0 + 8 < Wd) ? (float)rp[8] : 0.f;
    float cf[8];
#pragma unroll
    for (int p = 0; p < 8; ++p) cf[p] = (float)cv[p];
    float w0 = w[dr * 3], w1 = w[dr * 3 + 1], w2v = w[dr * 3 + 2];
#pragma unroll
    for (int p = 0; p < 8; ++p) {
      float l = (p == 0) ? lv : cf[p - 1];
      float rr = (p == 7) ? rv : cf[p + 1];
      acc[p] = fmaf(w0, l, acc[p]);
      acc[p] = fmaf(w1, cf[p], acc[p]);
      acc[p] = fmaf(w2v, rr, acc[p]);
    }
  }
  size_t off = ((size_t)(b * C + c)) * HW + i * Wd + j0;
  if constexpr (MODE == 1 || MODE == 2) {
    f16x8 o8;
#pragma unroll
    for (int p = 0; p < 8; ++p)
      o8[p] = (half_t)(MODE == 2 ? expf(acc[p]) : acc[p]);
    *(f16x8*)((half_t*)Zv + off) = o8;
  } else {
    float* op = (float*)Zv + off;
    *(float4*)op = make_float4(acc[0], acc[1], acc[2], acc[3]);
    *(float4*)(op + 4) = make_float4(acc[4], acc[5], acc[6], acc[7]);
  }
}

// ---------------- sum of ek per (b,c) row -> Sk ----------------
__global__ __launch_bounds__(256) void ksum(const half_t* __restrict__ EK,
                                            float* __restrict__ Sk) {
  int c = blockIdx.x, b = blockIdx.y;
  const half_t* p = EK + ((size_t)(b * C + c)) * HW;
  int t = threadIdx.x;
  float s = 0.f;
  for (int i = t * 8; i < HW; i += 2048) {
    f16x8 v = *(const f16x8*)(p + i);
#pragma unroll
    for (int j = 0; j < 8; ++j) s += (float)v[j];
  }
  __shared__ float red[256];
  red[t] = s; __syncthreads();
  for (int st = 128; st > 0; st >>= 1) {
    if (t < st) red[t] += red[t + st];
    __syncthreads();
  }
  if (t == 0) Sk[b * C + c] = red[0];
}

// ---------------- ctx_raw = EK @ V^T per head, pure MFMA ----------------
__global__ __launch_bounds__(256) void ctx_mfma(const half_t* __restrict__ EK,
                                                const half_t* __restrict__ V,
                                                float* __restrict__ part) {
  int bh = blockIdx.x, sp = blockIdx.y;
  int wave = threadIdx.x >> 6, lane = threadIdx.x & 63;
  int lr = lane & 15, lq = lane >> 4;
  const size_t base = (size_t)bh * HD * HW;
  const half_t* ekp = EK + base + (size_t)lr * HW;
  const half_t* vp  = V  + base + (size_t)lr * HW;
  f32x4 a00 = {0.f,0.f,0.f,0.f}, a01 = a00, a10 = a00, a11 = a00;
  const int n0w = sp * 1024 + wave * 256 + lq * 8;
#pragma unroll
  for (int ks = 0; ks < 8; ++ks) {
    int n = n0w + ks * 32;
    f16x8 fa0 = *(const f16x8*)(ekp + n);
    f16x8 fa1 = *(const f16x8*)(ekp + (size_t)16 * HW + n);
    f16x8 fb0 = *(const f16x8*)(vp + n);
    f16x8 fb1 = *(const f16x8*)(vp + (size_t)16 * HW + n);
    a00 = __builtin_amdgcn_mfma_f32_16x16x32_f16(fa0, fb0, a00, 0, 0, 0);
    a01 = __builtin_amdgcn_mfma_f32_16x16x32_f16(fa0, fb1, a01, 0, 0, 0);
    a10 = __builtin_amdgcn_mfma_f32_16x16x32_f16(fa1, fb0, a10, 0, 0, 0);
    a11 = __builtin_amdgcn_mfma_f32_16x16x32_f16(fa1, fb1, a11, 0, 0, 0);
  }
  __shared__ float red[4][1024];
#pragma unroll
  for (int j = 0; j < 4; ++j) {
    int dlo = lq * 4 + j;
    red[wave][(dlo)      * 32 + lr]      = a00[j];
    red[wave][(dlo)      * 32 + 16 + lr] = a01[j];
    red[wave][(dlo + 16) * 32 + lr]      = a10[j];
    red[wave][(dlo + 16) * 32 + 16 + lr] = a11[j];
  }
  __syncthreads();
  float* pp = part + ((size_t)sp * 32 + bh) * 1024;
  for (int idx = threadIdx.x; idx < 1024; idx += 256)
    pp[idx] = red[0][idx] + red[1][idx] + red[2][idx] + red[3][idx];
}

// ---------------- reduce ctx partials, apply 1/S, emit fp16 TRANSPOSED [e][d] ----------------
__global__ __launch_bounds__(256) void ctxred(const float* __restrict__ part,
                                              const float* __restrict__ Sk,
                                              half_t* __restrict__ ctxh) {
  int bh = blockIdx.x;
  int t = threadIdx.x;
  for (int idx = t; idx < 1024; idx += 256) {
    int d = idx >> 5, e = idx & 31;
    float s = 0.f;
#pragma unroll
    for (int sp = 0; sp < NSP; ++sp) s += part[((size_t)sp * 32 + bh) * 1024 + idx];
    ctxh[(size_t)bh * 1024 + e * 32 + d] = (half_t)(s / Sk[bh * HD + d]);
  }
}

// ---------------- attn5: P@ctx via MFMA; SiLU; swizzled LDS -> coalesced stores ----------------
__global__ __launch_bounds__(256) void attn5(const half_t* __restrict__ Qh,
                                             const half_t* __restrict__ ctxh,
                                             half_t* __restrict__ Oh) {
  const int b = blockIdx.y;
  const int lane = threadIdx.x & 63;
  const int w = threadIdx.x >> 6;
  const int lr = lane & 15, lq = lane >> 4;
  const int px = blockIdx.x * 64 + w * 16 + lr;       // A-row pixel for this lane
  __shared__ half_t osm[64 * 256];                    // 32KB output tile [px][c] swizzled

  f16x8 cf[HEADS][2];
#pragma unroll
  for (int h = 0; h < HEADS; ++h)
#pragma unroll
    for (int eh = 0; eh < 2; ++eh)
      cf[h][eh] = *(const f16x8*)(ctxh + ((size_t)(b * HEADS + h)) * 1024
                                  + (eh * 16 + lr) * 32 + lq * 8);

  const int pxl_base = w * 16 + lq * 4;               // D-row local pixel base
#pragma unroll
  for (int h = 0; h < HEADS; ++h) {
    const half_t* qp = Qh + ((size_t)(b * C + h * HD + lq * 8)) * HW + px;
    float ev[8];
    float psum = 0.f;
#pragma unroll
    for (int j = 0; j < 8; ++j) {
      ev[j] = expf((float)qp[(size_t)j * HW]);        // no max pass: logits bounded
      psum += ev[j];
    }
    float s = psum;
    s += __shfl_xor(s, 16, 64);
    s += __shfl_xor(s, 32, 64);                       // sum over 4 lq groups (fixed lr)
    float inv = 0.1767766952966369f / s;              // 32^-0.5 / s
    f16x8 pa;
#pragma unroll
    for (int j = 0; j < 8; ++j) pa[j] = (half_t)(ev[j] * inv);

    f32x4 z = {0.f, 0.f, 0.f, 0.f};
    f32x4 a0 = __builtin_amdgcn_mfma_f32_16x16x32_f16(pa, cf[h][0], z, 0, 0, 0);
    f32x4 a1 = __builtin_amdgcn_mfma_f32_16x16x32_f16(pa, cf[h][1], z, 0, 0, 0);

#pragma unroll
    for (int eh = 0; eh < 2; ++eh) {
      f32x4 a = eh ? a1 : a0;
      int c = h * 32 + eh * 16 + lr;
#pragma unroll
      for (int j = 0; j < 4; ++j) {
        int pxl = pxl_base + j;                       // D row = lq*4+j
        float v = a[j];
        float sg = 1.f / (1.f + expf(-v));
        int byte = pxl * 512 + ((c * 2) ^ (((pxl >> 2) & 7) << 4));
        *(half_t*)((char*)osm + byte) = (half_t)(v * sg * OSCALE);
      }
    }
  }
  __syncthreads();

  half_t* ob = Oh + ((size_t)b * HW + blockIdx.x * 64) * 256;
#pragma unroll
  for (int it = 0; it < 8; ++it) {
    int i = it * 256 + threadIdx.x;                   // 16B-chunk index, 2048 total
    int pxl = i >> 5;
    int inrow = (i & 31) * 16;
    int src = pxl * 512 + (inrow ^ (((pxl >> 2) & 7) << 4));
    *(f16x8*)(ob + (size_t)pxl * 256 + inrow / 2) = *(const f16x8*)((const char*)osm + src);
  }
}

extern "C" void kernel_launch(void* const* d_in, const int* in_sizes, int n_in,
                              void* d_out, int out_size, void* d_ws, size_t ws_size,
                              hipStream_t stream) {
  const float* fmap = (const float*)d_in[0];
  const float* g    = (const float*)d_in[1];
  const float* wq1  = (const float*)d_in[2];
  const float* wq2  = (const float*)d_in[3];
  const float* wk1  = (const float*)d_in[4];
  const float* wk2  = (const float*)d_in[5];
  const float* wv1  = (const float*)d_in[6];
  const float* wv2  = (const float*)d_in[7];
  const float* wout = (const float*)d_in[8];
  float* out = (float*)d_out;
  char* ws = (char*)d_ws;

  const size_t SZ = (size_t)B * C * HW;
  const size_t Mi = (size_t)1 << 20;
  // layout (byte offsets), live ranges audited:
  half_t* Xh   = (half_t*)(ws);                  // [0,32Mi)    ln2 -> gemm<0>
  half_t* Yh   = (half_t*)(ws + 32 * Mi);        // [32,128Mi)  Yq|Yk|Yv fp16
  half_t* Qh   = (half_t*)(ws + 128 * Mi);       // [128,160Mi) dwQ -> attn5
  half_t* EK   = (half_t*)(ws);                  // [0,32Mi)    exp(k) fp16 (Xh dead)
  half_t* Vh   = (half_t*)out;                   // d_out as fp16 V until ctx_mfma done
  float*  part = (float*)(ws + 96 * Mi);         // [96,98Mi)   over dead Yv
  float*  Sk   = (float*)(ws + 99 * Mi);         // 4KB
  half_t* ctxh = (half_t*)(ws + 100 * Mi);       // 64KB fp16 transposed [bh][e][d]
  half_t* Wh   = (half_t*)(ws + 192 * Mi);
  half_t* Woh  = (half_t*)(ws + 192 * Mi + 512 * 1024);
  half_t* Oh   = (half_t*)(ws + 32 * Mi);        // over dead Yq

  wcvt_all<<<dim3(1024), 256, 0, stream>>>(wq1, wk1, wv1, wout, Wh, Woh);

  ln2<<<dim3(HW / 64, B), 256, 0, stream>>>(fmap, g, Xh);

  gemm16p<0><<<dim3(6, HW / 128, B), 512, 0, stream>>>(Xh, Wh, Yh, nullptr);

  dw3x3_v<1><<<dim3(Hh / 16, C, B), 256, 0, stream>>>(Yh, wq2, Qh);            // Q fp16
  dw3x3_v<2><<<dim3(Hh / 16, C, B), 256, 0, stream>>>(Yh + SZ, wk2, EK);       // exp(K) fp16
  dw3x3_v<1><<<dim3(Hh / 16, C, B), 256, 0, stream>>>(Yh + 2 * SZ, wv2, Vh);   // V fp16

  ksum<<<dim3(C, B), 256, 0, stream>>>(EK, Sk);

  ctx_mfma<<<dim3(HEADS * B, NSP), 256, 0, stream>>>(EK, Vh, part);
  ctxred<<<dim3(32), 256, 0, stream>>>(part, Sk, ctxh);

  attn5<<<dim3(HW / 64, B), 256, 0, stream>>>(Qh, ctxh, Oh);

  gemm16p<1><<<dim3(2, HW / 128, B), 512, 0, stream>>>(Oh, Woh, nullptr, out);
}

// Round 15
// 209.709 us; speedup vs baseline: 1.0613x; 1.0559x over previous
//
#include <hip/hip_runtime.h>
#include <cmath>

// LinearAttention round 15.
// r14 + fix: Sk moved out of the Yv region (was zeroed by wcvt_all, then
// clobbered by gemm16w's Yv write, then atomicAdd'd garbage -> NaN).
// Sk now at ws+160Mi (gap between Qh and Wh; no other writer).

#define B 4
#define C 256
#define Hh 128
#define Wd 128
#define HW (Hh*Wd)
#define HEADS 8
#define HD 32
#define OSCALE 256.0f
#define NSP 16

typedef _Float16 half_t;
typedef _Float16 f16x8 __attribute__((ext_vector_type(8)));
typedef float f32x4 __attribute__((ext_vector_type(4)));

__device__ __forceinline__ void gload_lds16(const half_t* g, half_t* l) {
  __builtin_amdgcn_global_load_lds((const __attribute__((address_space(1))) void*)g,
                                   (__attribute__((address_space(3))) void*)l, 16, 0, 0);
}

// ---------------- all weights fp32 -> fp16 + zero Sk, one launch ----------------
__global__ __launch_bounds__(256) void wcvt_all(const float* __restrict__ wq1,
                                                const float* __restrict__ wk1,
                                                const float* __restrict__ wv1,
                                                const float* __restrict__ wout,
                                                half_t* __restrict__ Wh,
                                                half_t* __restrict__ Woh,
                                                float* __restrict__ Sk) {
  int i = blockIdx.x * 256 + threadIdx.x;  // grid 1024 -> 262144
  if (i < 65536) Wh[i] = (half_t)wq1[i];
  else if (i < 131072) Wh[i] = (half_t)wk1[i - 65536];
  else if (i < 196608) Wh[i] = (half_t)wv1[i - 131072];
  else Woh[i - 196608] = (half_t)wout[i - 196608];
  if (i < B * C) Sk[i] = 0.f;
}

// ---------------- channel LayerNorm -> X_h[b][pix][c] fp16 ----------------
__global__ __launch_bounds__(256) void ln2(const float* __restrict__ fmap,
                                           const float* __restrict__ g,
                                           half_t* __restrict__ Xh) {
  int b = blockIdx.y;
  int lane = threadIdx.x & 63;
  int gq = threadIdx.x >> 6;               // 0..3 channel group
  int px = blockIdx.x * 64 + lane;
  __shared__ float gs[C];
  __shared__ float sm1[4][64], sm2[4][64];
  gs[threadIdx.x] = g[threadIdx.x];
  const float* fp = fmap + ((size_t)b * C + gq * 64) * HW + px;
  float vbuf[64];
  float s = 0.f, s2 = 0.f;
#pragma unroll
  for (int j = 0; j < 64; ++j) {
    float v = fp[(size_t)j * HW];
    vbuf[j] = v;
    s += v; s2 = fmaf(v, v, s2);
  }
  sm1[gq][lane] = s; sm2[gq][lane] = s2;
  __syncthreads();
  float st = 0.f, st2 = 0.f;
#pragma unroll
  for (int q = 0; q < 4; ++q) { st += sm1[q][lane]; st2 += sm2[q][lane]; }
  float mean = st * (1.f / C);
  float var = st2 * (1.f / C) - mean * mean;
  float rstd = rsqrtf(var + 1e-5f);
  half_t* xp = Xh + ((size_t)b * HW + px) * 256 + gq * 64;
#pragma unroll
  for (int j0 = 0; j0 < 64; j0 += 8) {
    f16x8 v8;
#pragma unroll
    for (int jj = 0; jj < 8; ++jj)
      v8[jj] = (half_t)((vbuf[j0 + jj] - mean) * rstd * gs[gq * 64 + j0 + jj]);
    *(f16x8*)(xp + j0) = v8;
  }
}

// ---------------- fp16 MFMA GEMM (r12 proven): 512 thr, LDS-tile epilogue ----------------
__global__ __launch_bounds__(512) void gemm16w(const half_t* __restrict__ Xh,
                                               const half_t* __restrict__ Wh,
                                               half_t* __restrict__ Yh) {
  __shared__ __align__(16) char smem[65536];       // staging / out tile
  half_t* Xs0 = (half_t*)smem;
  half_t* Xs1 = (half_t*)(smem + 16384);
  half_t* Ws0 = (half_t*)(smem + 32768);
  half_t* Ws1 = (half_t*)(smem + 49152);
  const int tid = threadIdx.x;
  const int wave = tid >> 6, lane = tid & 63;
  const int lr = lane & 15, lq = lane >> 4;
  const int b = blockIdx.z;
  const int pix0 = blockIdx.x * 128;
  const int m0 = blockIdx.y * 128;
  const int wm = wave >> 1, wn = wave & 1;   // 4 m-waves x 2 px-waves

  const half_t* xb = Xh + ((size_t)b * HW + pix0) * 256;
  const half_t* wb = Wh + (size_t)m0 * 256;

  f32x4 acc[2][4];
#pragma unroll
  for (int i = 0; i < 2; ++i)
#pragma unroll
    for (int j = 0; j < 4; ++j) { f32x4 z = {0.f, 0.f, 0.f, 0.f}; acc[i][j] = z; }

#pragma unroll
  for (int it = 0; it < 2; ++it) {
    int e = it * 512 + tid, r = e >> 3, c = e & 7;   // 1024 chunks = 128 rows x 8
    int go = (c ^ (r & 7)) << 3;                     // inverse-swizzled SOURCE
    gload_lds16(xb + (size_t)r * 256 + go, Xs0 + e * 8);
    gload_lds16(wb + (size_t)r * 256 + go, Ws0 + e * 8);
  }
  __syncthreads();

#pragma unroll
  for (int kk = 0; kk < 4; ++kk) {
    half_t* Xsb = (kk & 1) ? Xs1 : Xs0;
    half_t* Wsb = (kk & 1) ? Ws1 : Ws0;
    if (kk < 3) {
      half_t* Xsn = (kk & 1) ? Xs0 : Xs1;
      half_t* Wsn = (kk & 1) ? Ws0 : Ws1;
#pragma unroll
      for (int it = 0; it < 2; ++it) {
        int e = it * 512 + tid, r = e >> 3, c = e & 7;
        int go = (kk + 1) * 64 + ((c ^ (r & 7)) << 3);
        gload_lds16(xb + (size_t)r * 256 + go, Xsn + e * 8);
        gload_lds16(wb + (size_t)r * 256 + go, Wsn + e * 8);
      }
    }
#pragma unroll
    for (int kf = 0; kf < 2; ++kf) {
      f16x8 afr[2], bfr[4];
#pragma unroll
      for (int mf = 0; mf < 2; ++mf) {
        int r = wm * 32 + mf * 16 + lr;
        int q = kf * 4 + lq;
        afr[mf] = *(const f16x8*)&Wsb[r * 64 + ((q ^ (r & 7)) << 3)];
      }
#pragma unroll
      for (int nf = 0; nf < 4; ++nf) {
        int r = wn * 64 + nf * 16 + lr;
        int q = kf * 4 + lq;
        bfr[nf] = *(const f16x8*)&Xsb[r * 64 + ((q ^ (r & 7)) << 3)];
      }
#pragma unroll
      for (int mf = 0; mf < 2; ++mf)
#pragma unroll
        for (int nf = 0; nf < 4; ++nf)
          acc[mf][nf] = __builtin_amdgcn_mfma_f32_16x16x32_f16(afr[mf], bfr[nf], acc[mf][nf], 0, 0, 0);
    }
    __syncthreads();
  }

  // epilogue via swizzled LDS tile -> 256B row bursts
#pragma unroll
  for (int mf = 0; mf < 2; ++mf)
#pragma unroll
    for (int nf = 0; nf < 4; ++nf)
#pragma unroll
      for (int j = 0; j < 4; ++j) {
        int row = wm * 32 + mf * 16 + lq * 4 + j;
        int col = wn * 64 + nf * 16 + lr;
        int byte = row * 256 + ((col * 2) ^ ((row & 7) << 4));
        *(half_t*)(smem + byte) = (half_t)acc[mf][nf][j];
      }
  __syncthreads();
  half_t* dst_base = Yh + (size_t)(m0 >> 8) * ((size_t)B * C * HW)
                     + ((size_t)(b * C + (m0 & 255))) * HW + pix0;
#pragma unroll
  for (int it = 0; it < 4; ++it) {
    int i = it * 512 + tid;                 // 2048 chunks = 128 rows x 16
    int row = i >> 4, ch = i & 15;
    int src = row * 256 + ((ch * 16) ^ ((row & 7) << 4));
    *(f16x8*)(dst_base + (size_t)row * HW + ch * 8) = *(const f16x8*)(smem + src);
  }
}

// ---------------- vectorized depthwise 3x3, fp16 out ----------------
__global__ __launch_bounds__(256) void dw3x3_v(const half_t* __restrict__ Yin,
                                               const float* __restrict__ W2,
                                               half_t* __restrict__ Zv) {
  int c = blockIdx.y, b = blockIdx.z;
  int r = threadIdx.x >> 4;
  int j0 = (threadIdx.x & 15) * 8;
  int i = blockIdx.x * 16 + r;
  const half_t* plane = Yin + ((size_t)(b * C + c)) * HW;
  float w[9];
#pragma unroll
  for (int k = 0; k < 9; ++k) w[k] = W2[c * 9 + k];
  float acc[8];
#pragma unroll
  for (int p = 0; p < 8; ++p) acc[p] = 0.f;
#pragma unroll
  for (int dr = 0; dr < 3; ++dr) {
    int ii = i + dr - 1;
    if (ii < 0 || ii >= Hh) continue;
    const half_t* rp = plane + ii * Wd + j0;
    f16x8 cv = *(const f16x8*)rp;
    float lv = (j0 > 0) ? (float)rp[-1] : 0.f;
    float rv = (j0 + 8 < Wd) ? (float)rp[8] : 0.f;
    float cf[8];
#pragma unroll
    for (int p = 0; p < 8; ++p) cf[p] = (float)cv[p];
    float w0 = w[dr * 3], w1 = w[dr * 3 + 1], w2v = w[dr * 3 + 2];
#pragma unroll
    for (int p = 0; p < 8; ++p) {
      float l = (p == 0) ? lv : cf[p - 1];
      float rr = (p == 7) ? rv : cf[p + 1];
      acc[p] = fmaf(w0, l, acc[p]);
      acc[p] = fmaf(w1, cf[p], acc[p]);
      acc[p] = fmaf(w2v, rr, acc[p]);
    }
  }
  size_t off = ((size_t)(b * C + c)) * HW + i * Wd + j0;
  f16x8 o8;
#pragma unroll
  for (int p = 0; p < 8; ++p) o8[p] = (half_t)acc[p];
  *(f16x8*)(Zv + off) = o8;
}

// ---------------- dw3x3 K-path: fp16 exp(out) + fused channel-sum (atomicAdd) ----------------
__global__ __launch_bounds__(256) void dw3x3_k(const half_t* __restrict__ Yin,
                                               const float* __restrict__ W2,
                                               half_t* __restrict__ Zv,
                                               float* __restrict__ Sk) {
  int c = blockIdx.y, b = blockIdx.z;
  int r = threadIdx.x >> 4;
  int j0 = (threadIdx.x & 15) * 8;
  int i = blockIdx.x * 16 + r;
  const half_t* plane = Yin + ((size_t)(b * C + c)) * HW;
  float w[9];
#pragma unroll
  for (int k = 0; k < 9; ++k) w[k] = W2[c * 9 + k];
  float acc[8];
#pragma unroll
  for (int p = 0; p < 8; ++p) acc[p] = 0.f;
#pragma unroll
  for (int dr = 0; dr < 3; ++dr) {
    int ii = i + dr - 1;
    if (ii < 0 || ii >= Hh) continue;
    const half_t* rp = plane + ii * Wd + j0;
    f16x8 cv = *(const f16x8*)rp;
    float lv = (j0 > 0) ? (float)rp[-1] : 0.f;
    float rv = (j0 + 8 < Wd) ? (float)rp[8] : 0.f;
    float cf[8];
#pragma unroll
    for (int p = 0; p < 8; ++p) cf[p] = (float)cv[p];
    float w0 = w[dr * 3], w1 = w[dr * 3 + 1], w2v = w[dr * 3 + 2];
#pragma unroll
    for (int p = 0; p < 8; ++p) {
      float l = (p == 0) ? lv : cf[p - 1];
      float rr = (p == 7) ? rv : cf[p + 1];
      acc[p] = fmaf(w0, l, acc[p]);
      acc[p] = fmaf(w1, cf[p], acc[p]);
      acc[p] = fmaf(w2v, rr, acc[p]);
    }
  }
  size_t off = ((size_t)(b * C + c)) * HW + i * Wd + j0;
  f16x8 o8;
  float local = 0.f;
#pragma unroll
  for (int p = 0; p < 8; ++p) {
    float e = expf(acc[p]);          // logits ~N(0,small): no max pass needed
    o8[p] = (half_t)e;
    local += e;
  }
  *(f16x8*)(Zv + off) = o8;
  __shared__ float red[256];
  int t = threadIdx.x;
  red[t] = local; __syncthreads();
  for (int st = 128; st > 0; st >>= 1) {
    if (t < st) red[t] += red[t + st];
    __syncthreads();
  }
  if (t == 0) atomicAdd(&Sk[b * C + c], red[0]);
}

// ---------------- ctx_raw = EK @ V^T per head, pure MFMA ----------------
__global__ __launch_bounds__(256) void ctx_mfma(const half_t* __restrict__ EK,
                                                const half_t* __restrict__ V,
                                                float* __restrict__ part) {
  int bh = blockIdx.x, sp = blockIdx.y;
  int wave = threadIdx.x >> 6, lane = threadIdx.x & 63;
  int lr = lane & 15, lq = lane >> 4;
  const size_t base = (size_t)bh * HD * HW;
  const half_t* ekp = EK + base + (size_t)lr * HW;
  const half_t* vp  = V  + base + (size_t)lr * HW;
  f32x4 a00 = {0.f,0.f,0.f,0.f}, a01 = a00, a10 = a00, a11 = a00;
  const int n0w = sp * 1024 + wave * 256 + lq * 8;
#pragma unroll
  for (int ks = 0; ks < 8; ++ks) {
    int n = n0w + ks * 32;
    f16x8 fa0 = *(const f16x8*)(ekp + n);
    f16x8 fa1 = *(const f16x8*)(ekp + (size_t)16 * HW + n);
    f16x8 fb0 = *(const f16x8*)(vp + n);
    f16x8 fb1 = *(const f16x8*)(vp + (size_t)16 * HW + n);
    a00 = __builtin_amdgcn_mfma_f32_16x16x32_f16(fa0, fb0, a00, 0, 0, 0);
    a01 = __builtin_amdgcn_mfma_f32_16x16x32_f16(fa0, fb1, a01, 0, 0, 0);
    a10 = __builtin_amdgcn_mfma_f32_16x16x32_f16(fa1, fb0, a10, 0, 0, 0);
    a11 = __builtin_amdgcn_mfma_f32_16x16x32_f16(fa1, fb1, a11, 0, 0, 0);
  }
  __shared__ float red[4][1024];
#pragma unroll
  for (int j = 0; j < 4; ++j) {
    int dlo = lq * 4 + j;
    red[wave][(dlo)      * 32 + lr]      = a00[j];
    red[wave][(dlo)      * 32 + 16 + lr] = a01[j];
    red[wave][(dlo + 16) * 32 + lr]      = a10[j];
    red[wave][(dlo + 16) * 32 + 16 + lr] = a11[j];
  }
  __syncthreads();
  float* pp = part + ((size_t)sp * 32 + bh) * 1024;
  for (int idx = threadIdx.x; idx < 1024; idx += 256)
    pp[idx] = red[0][idx] + red[1][idx] + red[2][idx] + red[3][idx];
}

// ---------------- reduce ctx partials, apply 1/S, emit fp16 TRANSPOSED [e][d] ----------------
__global__ __launch_bounds__(256) void ctxred(const float* __restrict__ part,
                                              const float* __restrict__ Sk,
                                              half_t* __restrict__ ctxh) {
  int bh = blockIdx.x;
  int t = threadIdx.x;
  for (int idx = t; idx < 1024; idx += 256) {
    int d = idx >> 5, e = idx & 31;
    float s = 0.f;
#pragma unroll
    for (int sp = 0; sp < NSP; ++sp) s += part[((size_t)sp * 32 + bh) * 1024 + idx];
    ctxh[(size_t)bh * 1024 + e * 32 + d] = (half_t)(s / Sk[bh * HD + d]);
  }
}

// ---------------- attn6: P@ctx (MFMA) -> SiLU -> LDS O tile -> O@Wout^T -> fp32 out ----------------
// grid (HW/64, B), block 256 = 4 waves.
__global__ __launch_bounds__(256) void attn6(const half_t* __restrict__ Qh,
                                             const half_t* __restrict__ ctxh,
                                             const half_t* __restrict__ Woh,
                                             float* __restrict__ outp) {
  const int b = blockIdx.y;
  const int lane = threadIdx.x & 63;
  const int w = threadIdx.x >> 6;
  const int lr = lane & 15, lq = lane >> 4;
  const int px0 = blockIdx.x * 64;
  const int px = px0 + w * 16 + lr;                   // phase-1 A-row pixel
  __shared__ __align__(16) char osm[64 * 512];        // 32KB O tile [px][c] fp16 swizzled

  // ---- phase 1: O = silu(softmax(q) @ ctx) * OSCALE ----
  {
    f16x8 cf[HEADS][2];
#pragma unroll
    for (int h = 0; h < HEADS; ++h)
#pragma unroll
      for (int eh = 0; eh < 2; ++eh)
        cf[h][eh] = *(const f16x8*)(ctxh + ((size_t)(b * HEADS + h)) * 1024
                                    + (eh * 16 + lr) * 32 + lq * 8);
    const int pxl_base = w * 16 + lq * 4;
#pragma unroll
    for (int h = 0; h < HEADS; ++h) {
      const half_t* qp = Qh + ((size_t)(b * C + h * HD + lq * 8)) * HW + px;
      float ev[8];
      float psum = 0.f;
#pragma unroll
      for (int j = 0; j < 8; ++j) {
        ev[j] = expf((float)qp[(size_t)j * HW]);      // no max pass: logits bounded
        psum += ev[j];
      }
      float s = psum;
      s += __shfl_xor(s, 16, 64);
      s += __shfl_xor(s, 32, 64);
      float inv = 0.1767766952966369f / s;            // 32^-0.5 / s
      f16x8 pa;
#pragma unroll
      for (int j = 0; j < 8; ++j) pa[j] = (half_t)(ev[j] * inv);

      f32x4 z = {0.f, 0.f, 0.f, 0.f};
      f32x4 a0 = __builtin_amdgcn_mfma_f32_16x16x32_f16(pa, cf[h][0], z, 0, 0, 0);
      f32x4 a1 = __builtin_amdgcn_mfma_f32_16x16x32_f16(pa, cf[h][1], z, 0, 0, 0);
#pragma unroll
      for (int eh = 0; eh < 2; ++eh) {
        f32x4 a = eh ? a1 : a0;
        int cc = h * 32 + eh * 16 + lr;
#pragma unroll
        for (int j = 0; j < 4; ++j) {
          int pxl = pxl_base + j;
          float v = a[j];
          float sg = 1.f / (1.f + expf(-v));
          int byte = pxl * 512 + ((cc * 2) ^ ((pxl & 7) << 4));
          *(half_t*)(osm + byte) = (half_t)(v * sg * OSCALE);
        }
      }
    }
  }
  __syncthreads();

  // ---- phase 2: out = O @ Woh^T / OSCALE ----
  f32x4 acc[4][4];
#pragma unroll
  for (int i = 0; i < 4; ++i)
#pragma unroll
    for (int j = 0; j < 4; ++j) { f32x4 z = {0.f, 0.f, 0.f, 0.f}; acc[i][j] = z; }

  const half_t* wbase = Woh + ((size_t)(w * 64 + lr)) * 256 + lq * 8;
#pragma unroll
  for (int k0 = 0; k0 < 256; k0 += 32) {
    f16x8 afr[4], bfr[4];
#pragma unroll
    for (int mf = 0; mf < 4; ++mf)
      afr[mf] = *(const f16x8*)(wbase + (size_t)(mf * 16) * 256 + k0);
#pragma unroll
    for (int nf = 0; nf < 4; ++nf) {
      int r = nf * 16 + lr;
      bfr[nf] = *(const f16x8*)(osm + r * 512 + ((k0 * 2 + lq * 16) ^ ((r & 7) << 4)));
    }
#pragma unroll
    for (int mf = 0; mf < 4; ++mf)
#pragma unroll
      for (int nf = 0; nf < 4; ++nf)
        acc[mf][nf] = __builtin_amdgcn_mfma_f32_16x16x32_f16(afr[mf], bfr[nf], acc[mf][nf], 0, 0, 0);
  }

  // D[row=oc][col=px]; fp32 stores, 16 lanes consecutive px = 64B segments
#pragma unroll
  for (int mf = 0; mf < 4; ++mf) {
    int oc = w * 64 + mf * 16 + lq * 4;
#pragma unroll
    for (int nf = 0; nf < 4; ++nf) {
      float* dst = outp + ((size_t)(b * C + oc)) * HW + px0 + nf * 16 + lr;
#pragma unroll
      for (int j = 0; j < 4; ++j)
        dst[(size_t)j * HW] = acc[mf][nf][j] * (1.0f / OSCALE);
    }
  }
}

extern "C" void kernel_launch(void* const* d_in, const int* in_sizes, int n_in,
                              void* d_out, int out_size, void* d_ws, size_t ws_size,
                              hipStream_t stream) {
  const float* fmap = (const float*)d_in[0];
  const float* g    = (const float*)d_in[1];
  const float* wq1  = (const float*)d_in[2];
  const float* wq2  = (const float*)d_in[3];
  const float* wk1  = (const float*)d_in[4];
  const float* wk2  = (const float*)d_in[5];
  const float* wv1  = (const float*)d_in[6];
  const float* wv2  = (const float*)d_in[7];
  const float* wout = (const float*)d_in[8];
  float* out = (float*)d_out;
  char* ws = (char*)d_ws;

  const size_t SZ = (size_t)B * C * HW;
  const size_t Mi = (size_t)1 << 20;
  // layout (byte offsets), live ranges audited:
  half_t* Xh   = (half_t*)(ws);                  // [0,32Mi)    ln2 -> gemm
  half_t* Yh   = (half_t*)(ws + 32 * Mi);        // [32,128Mi)  Yq|Yk|Yv fp16
  half_t* Qh   = (half_t*)(ws + 128 * Mi);       // [128,160Mi) dwQ -> attn6
  half_t* EK   = (half_t*)(ws);                  // [0,32Mi)    exp(k) fp16 (Xh dead)
  half_t* Vh   = (half_t*)out;                   // d_out as fp16 V until attn6 overwrites
  float*  part = (float*)(ws + 96 * Mi);         // [96,98Mi)   over dead Yv (full overwrite)
  float*  Sk   = (float*)(ws + 160 * Mi);        // 4KB — OUTSIDE Yv (zero+accumulate lifetime)
  half_t* ctxh = (half_t*)(ws + 100 * Mi);       // 64KB over dead Yv (full overwrite)
  half_t* Wh   = (half_t*)(ws + 192 * Mi);
  half_t* Woh  = (half_t*)(ws + 192 * Mi + 512 * 1024);

  wcvt_all<<<dim3(1024), 256, 0, stream>>>(wq1, wk1, wv1, wout, Wh, Woh, Sk);

  ln2<<<dim3(HW / 64, B), 256, 0, stream>>>(fmap, g, Xh);

  gemm16w<<<dim3(HW / 128, 6, B), 512, 0, stream>>>(Xh, Wh, Yh);

  dw3x3_v<<<dim3(Hh / 16, C, B), 256, 0, stream>>>(Yh, wq2, Qh);               // Q fp16
  dw3x3_k<<<dim3(Hh / 16, C, B), 256, 0, stream>>>(Yh + SZ, wk2, EK, Sk);      // exp(K) + sum
  dw3x3_v<<<dim3(Hh / 16, C, B), 256, 0, stream>>>(Yh + 2 * SZ, wv2, Vh);      // V fp16

  ctx_mfma<<<dim3(HEADS * B, NSP), 256, 0, stream>>>(EK, Vh, part);
  ctxred<<<dim3(32), 256, 0, stream>>>(part, Sk, ctxh);

  attn6<<<dim3(HW / 64, B), 256, 0, stream>>>(Qh, ctxh, Woh, out);
}

// Round 16
// 198.464 us; speedup vs baseline: 1.1215x; 1.0567x over previous
//
#include <hip/hip_runtime.h>
#include <cmath>

// LinearAttention round 16.
// vs r15: (1) gemm16r = r13's BK=32 ring-4 counted-vmcnt pipeline with r12's
// grid mapping (deconfounds r13's grid-swap regression); (2) attn6b loads ctx
// fragments per-head (frees 64 pinned VGPRs, 84->~55, occupancy up).

#define B 4
#define C 256
#define Hh 128
#define Wd 128
#define HW (Hh*Wd)
#define HEADS 8
#define HD 32
#define OSCALE 256.0f
#define NSP 16

typedef _Float16 half_t;
typedef _Float16 f16x8 __attribute__((ext_vector_type(8)));
typedef float f32x4 __attribute__((ext_vector_type(4)));

__device__ __forceinline__ void gload_lds16(const half_t* g, half_t* l) {
  __builtin_amdgcn_global_load_lds((const __attribute__((address_space(1))) void*)g,
                                   (__attribute__((address_space(3))) void*)l, 16, 0, 0);
}

// ---------------- all weights fp32 -> fp16 + zero Sk, one launch ----------------
__global__ __launch_bounds__(256) void wcvt_all(const float* __restrict__ wq1,
                                                const float* __restrict__ wk1,
                                                const float* __restrict__ wv1,
                                                const float* __restrict__ wout,
                                                half_t* __restrict__ Wh,
                                                half_t* __restrict__ Woh,
                                                float* __restrict__ Sk) {
  int i = blockIdx.x * 256 + threadIdx.x;  // grid 1024 -> 262144
  if (i < 65536) Wh[i] = (half_t)wq1[i];
  else if (i < 131072) Wh[i] = (half_t)wk1[i - 65536];
  else if (i < 196608) Wh[i] = (half_t)wv1[i - 131072];
  else Woh[i - 196608] = (half_t)wout[i - 196608];
  if (i < B * C) Sk[i] = 0.f;
}

// ---------------- channel LayerNorm -> X_h[b][pix][c] fp16 ----------------
__global__ __launch_bounds__(256) void ln2(const float* __restrict__ fmap,
                                           const float* __restrict__ g,
                                           half_t* __restrict__ Xh) {
  int b = blockIdx.y;
  int lane = threadIdx.x & 63;
  int gq = threadIdx.x >> 6;               // 0..3 channel group
  int px = blockIdx.x * 64 + lane;
  __shared__ float gs[C];
  __shared__ float sm1[4][64], sm2[4][64];
  gs[threadIdx.x] = g[threadIdx.x];
  const float* fp = fmap + ((size_t)b * C + gq * 64) * HW + px;
  float vbuf[64];
  float s = 0.f, s2 = 0.f;
#pragma unroll
  for (int j = 0; j < 64; ++j) {
    float v = fp[(size_t)j * HW];
    vbuf[j] = v;
    s += v; s2 = fmaf(v, v, s2);
  }
  sm1[gq][lane] = s; sm2[gq][lane] = s2;
  __syncthreads();
  float st = 0.f, st2 = 0.f;
#pragma unroll
  for (int q = 0; q < 4; ++q) { st += sm1[q][lane]; st2 += sm2[q][lane]; }
  float mean = st * (1.f / C);
  float var = st2 * (1.f / C) - mean * mean;
  float rstd = rsqrtf(var + 1e-5f);
  half_t* xp = Xh + ((size_t)b * HW + px) * 256 + gq * 64;
#pragma unroll
  for (int j0 = 0; j0 < 64; j0 += 8) {
    f16x8 v8;
#pragma unroll
    for (int jj = 0; jj < 8; ++jj)
      v8[jj] = (half_t)((vbuf[j0 + jj] - mean) * rstd * gs[gq * 64 + j0 + jj]);
    *(f16x8*)(xp + j0) = v8;
  }
}

// ---------------- fp16 MFMA GEMM: BK=32 ring-4, counted vmcnt, r12 grid ----------------
// Y[m][pix] = sum_c W[m][c] X[pix][c]. Tile 128m x 128px, 8 waves (4m x 2px).
// Ring slot s (16KB): X[128rows][4x16B chunks] then W at +8192.
// Chunk XOR: lds_chunk = g_chunk ^ ((row>>1)&3)  (2-way on ds_read = free).
__global__ __launch_bounds__(512) void gemm16r(const half_t* __restrict__ Xh,
                                               const half_t* __restrict__ Wh,
                                               half_t* __restrict__ Yh) {
  __shared__ __align__(16) char smem[65536];       // 4 ring slots / out tile
  const int tid = threadIdx.x;
  const int wave = tid >> 6, lane = tid & 63;
  const int lr = lane & 15, lq = lane >> 4;
  const int b = blockIdx.z;
  const int pix0 = blockIdx.x * 128;               // x = pix (r12 mapping)
  const int m0 = blockIdx.y * 128;
  const int wm = wave >> 1, wn = wave & 1;         // 4 m-waves x 2 px-waves

  const half_t* xb = Xh + ((size_t)b * HW + pix0) * 256;
  const half_t* wb = Wh + (size_t)m0 * 256;

  f32x4 acc[2][4];
#pragma unroll
  for (int i = 0; i < 2; ++i)
#pragma unroll
    for (int j = 0; j < 4; ++j) { f32x4 z = {0.f, 0.f, 0.f, 0.f}; acc[i][j] = z; }

#define STAGE(kt, s) do {                                                       \
    int r_ = tid >> 2, c_ = tid & 3;                                            \
    int cs_ = c_ ^ ((r_ >> 1) & 3);                                             \
    gload_lds16(xb + (size_t)r_ * 256 + (kt) * 32 + (cs_ << 3),                 \
                (half_t*)(smem + (s) * 16384) + tid * 8);                       \
    gload_lds16(wb + (size_t)r_ * 256 + (kt) * 32 + (cs_ << 3),                 \
                (half_t*)(smem + (s) * 16384 + 8192) + tid * 8);                \
  } while (0)

  STAGE(0, 0);
  STAGE(1, 1);

#pragma unroll
  for (int t = 0; t < 8; ++t) {
    if (t < 6) STAGE(t + 2, (t + 2) & 3);
    if (t < 6)       asm volatile("s_waitcnt vmcnt(4)" ::: "memory");
    else if (t == 6) asm volatile("s_waitcnt vmcnt(2)" ::: "memory");
    else             asm volatile("s_waitcnt vmcnt(0)" ::: "memory");
    __builtin_amdgcn_sched_barrier(0);
    __builtin_amdgcn_s_barrier();                  // all waves: tile t landed
    const char* slot = smem + (t & 3) * 16384;
    f16x8 afr[2], bfr[4];
#pragma unroll
    for (int mf = 0; mf < 2; ++mf) {
      int r = wm * 32 + mf * 16 + lr;
      afr[mf] = *(const f16x8*)(slot + 8192 + r * 64 + ((lq ^ ((r >> 1) & 3)) << 4));
    }
#pragma unroll
    for (int nf = 0; nf < 4; ++nf) {
      int r = wn * 64 + nf * 16 + lr;
      bfr[nf] = *(const f16x8*)(slot + r * 64 + ((lq ^ ((r >> 1) & 3)) << 4));
    }
#pragma unroll
    for (int mf = 0; mf < 2; ++mf)
#pragma unroll
      for (int nf = 0; nf < 4; ++nf)
        acc[mf][nf] = __builtin_amdgcn_mfma_f32_16x16x32_f16(afr[mf], bfr[nf], acc[mf][nf], 0, 0, 0);
  }
#undef STAGE
  asm volatile("s_waitcnt lgkmcnt(0)" ::: "memory");
  __builtin_amdgcn_sched_barrier(0);
  __builtin_amdgcn_s_barrier();                    // smem free for out tile

  // epilogue via swizzled LDS tile -> 256B row bursts
#pragma unroll
  for (int mf = 0; mf < 2; ++mf)
#pragma unroll
    for (int nf = 0; nf < 4; ++nf)
#pragma unroll
      for (int j = 0; j < 4; ++j) {
        int row = wm * 32 + mf * 16 + lq * 4 + j;
        int col = wn * 64 + nf * 16 + lr;
        int byte = row * 256 + ((col * 2) ^ ((row & 7) << 4));
        *(half_t*)(smem + byte) = (half_t)acc[mf][nf][j];
      }
  __syncthreads();
  half_t* dst_base = Yh + (size_t)(m0 >> 8) * ((size_t)B * C * HW)
                     + ((size_t)(b * C + (m0 & 255))) * HW + pix0;
#pragma unroll
  for (int it = 0; it < 4; ++it) {
    int i = it * 512 + tid;                 // 2048 chunks = 128 rows x 16
    int row = i >> 4, ch = i & 15;
    int src = row * 256 + ((ch * 16) ^ ((row & 7) << 4));
    *(f16x8*)(dst_base + (size_t)row * HW + ch * 8) = *(const f16x8*)(smem + src);
  }
}

// ---------------- vectorized depthwise 3x3, fp16 out ----------------
__global__ __launch_bounds__(256) void dw3x3_v(const half_t* __restrict__ Yin,
                                               const float* __restrict__ W2,
                                               half_t* __restrict__ Zv) {
  int c = blockIdx.y, b = blockIdx.z;
  int r = threadIdx.x >> 4;
  int j0 = (threadIdx.x & 15) * 8;
  int i = blockIdx.x * 16 + r;
  const half_t* plane = Yin + ((size_t)(b * C + c)) * HW;
  float w[9];
#pragma unroll
  for (int k = 0; k < 9; ++k) w[k] = W2[c * 9 + k];
  float acc[8];
#pragma unroll
  for (int p = 0; p < 8; ++p) acc[p] = 0.f;
#pragma unroll
  for (int dr = 0; dr < 3; ++dr) {
    int ii = i + dr - 1;
    if (ii < 0 || ii >= Hh) continue;
    const half_t* rp = plane + ii * Wd + j0;
    f16x8 cv = *(const f16x8*)rp;
    float lv = (j0 > 0) ? (float)rp[-1] : 0.f;
    float rv = (j0 + 8 < Wd) ? (float)rp[8] : 0.f;
    float cf[8];
#pragma unroll
    for (int p = 0; p < 8; ++p) cf[p] = (float)cv[p];
    float w0 = w[dr * 3], w1 = w[dr * 3 + 1], w2v = w[dr * 3 + 2];
#pragma unroll
    for (int p = 0; p < 8; ++p) {
      float l = (p == 0) ? lv : cf[p - 1];
      float rr = (p == 7) ? rv : cf[p + 1];
      acc[p] = fmaf(w0, l, acc[p]);
      acc[p] = fmaf(w1, cf[p], acc[p]);
      acc[p] = fmaf(w2v, rr, acc[p]);
    }
  }
  size_t off = ((size_t)(b * C + c)) * HW + i * Wd + j0;
  f16x8 o8;
#pragma unroll
  for (int p = 0; p < 8; ++p) o8[p] = (half_t)acc[p];
  *(f16x8*)(Zv + off) = o8;
}

// ---------------- dw3x3 K-path: fp16 exp(out) + fused channel-sum (atomicAdd) ----------------
__global__ __launch_bounds__(256) void dw3x3_k(const half_t* __restrict__ Yin,
                                               const float* __restrict__ W2,
                                               half_t* __restrict__ Zv,
                                               float* __restrict__ Sk) {
  int c = blockIdx.y, b = blockIdx.z;
  int r = threadIdx.x >> 4;
  int j0 = (threadIdx.x & 15) * 8;
  int i = blockIdx.x * 16 + r;
  const half_t* plane = Yin + ((size_t)(b * C + c)) * HW;
  float w[9];
#pragma unroll
  for (int k = 0; k < 9; ++k) w[k] = W2[c * 9 + k];
  float acc[8];
#pragma unroll
  for (int p = 0; p < 8; ++p) acc[p] = 0.f;
#pragma unroll
  for (int dr = 0; dr < 3; ++dr) {
    int ii = i + dr - 1;
    if (ii < 0 || ii >= Hh) continue;
    const half_t* rp = plane + ii * Wd + j0;
    f16x8 cv = *(const f16x8*)rp;
    float lv = (j0 > 0) ? (float)rp[-1] : 0.f;
    float rv = (j0 + 8 < Wd) ? (float)rp[8] : 0.f;
    float cf[8];
#pragma unroll
    for (int p = 0; p < 8; ++p) cf[p] = (float)cv[p];
    float w0 = w[dr * 3], w1 = w[dr * 3 + 1], w2v = w[dr * 3 + 2];
#pragma unroll
    for (int p = 0; p < 8; ++p) {
      float l = (p == 0) ? lv : cf[p - 1];
      float rr = (p == 7) ? rv : cf[p + 1];
      acc[p] = fmaf(w0, l, acc[p]);
      acc[p] = fmaf(w1, cf[p], acc[p]);
      acc[p] = fmaf(w2v, rr, acc[p]);
    }
  }
  size_t off = ((size_t)(b * C + c)) * HW + i * Wd + j0;
  f16x8 o8;
  float local = 0.f;
#pragma unroll
  for (int p = 0; p < 8; ++p) {
    float e = expf(acc[p]);          // logits ~N(0,small): no max pass needed
    o8[p] = (half_t)e;
    local += e;
  }
  *(f16x8*)(Zv + off) = o8;
  __shared__ float red[256];
  int t = threadIdx.x;
  red[t] = local; __syncthreads();
  for (int st = 128; st > 0; st >>= 1) {
    if (t < st) red[t] += red[t + st];
    __syncthreads();
  }
  if (t == 0) atomicAdd(&Sk[b * C + c], red[0]);
}

// ---------------- ctx_raw = EK @ V^T per head, pure MFMA ----------------
__global__ __launch_bounds__(256) void ctx_mfma(const half_t* __restrict__ EK,
                                                const half_t* __restrict__ V,
                                                float* __restrict__ part) {
  int bh = blockIdx.x, sp = blockIdx.y;
  int wave = threadIdx.x >> 6, lane = threadIdx.x & 63;
  int lr = lane & 15, lq = lane >> 4;
  const size_t base = (size_t)bh * HD * HW;
  const half_t* ekp = EK + base + (size_t)lr * HW;
  const half_t* vp  = V  + base + (size_t)lr * HW;
  f32x4 a00 = {0.f,0.f,0.f,0.f}, a01 = a00, a10 = a00, a11 = a00;
  const int n0w = sp * 1024 + wave * 256 + lq * 8;
#pragma unroll
  for (int ks = 0; ks < 8; ++ks) {
    int n = n0w + ks * 32;
    f16x8 fa0 = *(const f16x8*)(ekp + n);
    f16x8 fa1 = *(const f16x8*)(ekp + (size_t)16 * HW + n);
    f16x8 fb0 = *(const f16x8*)(vp + n);
    f16x8 fb1 = *(const f16x8*)(vp + (size_t)16 * HW + n);
    a00 = __builtin_amdgcn_mfma_f32_16x16x32_f16(fa0, fb0, a00, 0, 0, 0);
    a01 = __builtin_amdgcn_mfma_f32_16x16x32_f16(fa0, fb1, a01, 0, 0, 0);
    a10 = __builtin_amdgcn_mfma_f32_16x16x32_f16(fa1, fb0, a10, 0, 0, 0);
    a11 = __builtin_amdgcn_mfma_f32_16x16x32_f16(fa1, fb1, a11, 0, 0, 0);
  }
  __shared__ float red[4][1024];
#pragma unroll
  for (int j = 0; j < 4; ++j) {
    int dlo = lq * 4 + j;
    red[wave][(dlo)      * 32 + lr]      = a00[j];
    red[wave][(dlo)      * 32 + 16 + lr] = a01[j];
    red[wave][(dlo + 16) * 32 + lr]      = a10[j];
    red[wave][(dlo + 16) * 32 + 16 + lr] = a11[j];
  }
  __syncthreads();
  float* pp = part + ((size_t)sp * 32 + bh) * 1024;
  for (int idx = threadIdx.x; idx < 1024; idx += 256)
    pp[idx] = red[0][idx] + red[1][idx] + red[2][idx] + red[3][idx];
}

// ---------------- reduce ctx partials, apply 1/S, emit fp16 TRANSPOSED [e][d] ----------------
__global__ __launch_bounds__(256) void ctxred(const float* __restrict__ part,
                                              const float* __restrict__ Sk,
                                              half_t* __restrict__ ctxh) {
  int bh = blockIdx.x;
  int t = threadIdx.x;
  for (int idx = t; idx < 1024; idx += 256) {
    int d = idx >> 5, e = idx & 31;
    float s = 0.f;
#pragma unroll
    for (int sp = 0; sp < NSP; ++sp) s += part[((size_t)sp * 32 + bh) * 1024 + idx];
    ctxh[(size_t)bh * 1024 + e * 32 + d] = (half_t)(s / Sk[bh * HD + d]);
  }
}

// ---------------- attn6b: P@ctx (MFMA) -> SiLU -> LDS O tile -> O@Wout^T -> fp32 out ----------------
// grid (HW/64, B), block 256 = 4 waves. ctx fragments loaded per-head (no 64-VGPR pin).
__global__ __launch_bounds__(256) void attn6b(const half_t* __restrict__ Qh,
                                              const half_t* __restrict__ ctxh,
                                              const half_t* __restrict__ Woh,
                                              float* __restrict__ outp) {
  const int b = blockIdx.y;
  const int lane = threadIdx.x & 63;
  const int w = threadIdx.x >> 6;
  const int lr = lane & 15, lq = lane >> 4;
  const int px0 = blockIdx.x * 64;
  const int px = px0 + w * 16 + lr;                   // phase-1 A-row pixel
  __shared__ __align__(16) char osm[64 * 512];        // 32KB O tile [px][c] fp16 swizzled

  // ---- phase 1: O = silu(softmax(q) @ ctx) * OSCALE ----
  {
    const int pxl_base = w * 16 + lq * 4;
#pragma unroll
    for (int h = 0; h < HEADS; ++h) {
      // ctx B-fragments for this head only (L2-resident, 2 x f16x8)
      const half_t* cb = ctxh + ((size_t)(b * HEADS + h)) * 1024;
      f16x8 cf0 = *(const f16x8*)(cb + (lr)      * 32 + lq * 8);
      f16x8 cf1 = *(const f16x8*)(cb + (16 + lr) * 32 + lq * 8);

      const half_t* qp = Qh + ((size_t)(b * C + h * HD + lq * 8)) * HW + px;
      float ev[8];
      float psum = 0.f;
#pragma unroll
      for (int j = 0; j < 8; ++j) {
        ev[j] = expf((float)qp[(size_t)j * HW]);      // no max pass: logits bounded
        psum += ev[j];
      }
      float s = psum;
      s += __shfl_xor(s, 16, 64);
      s += __shfl_xor(s, 32, 64);
      float inv = 0.1767766952966369f / s;            // 32^-0.5 / s
      f16x8 pa;
#pragma unroll
      for (int j = 0; j < 8; ++j) pa[j] = (half_t)(ev[j] * inv);

      f32x4 z = {0.f, 0.f, 0.f, 0.f};
      f32x4 a0 = __builtin_amdgcn_mfma_f32_16x16x32_f16(pa, cf0, z, 0, 0, 0);
      f32x4 a1 = __builtin_amdgcn_mfma_f32_16x16x32_f16(pa, cf1, z, 0, 0, 0);
#pragma unroll
      for (int eh = 0; eh < 2; ++eh) {
        f32x4 a = eh ? a1 : a0;
        int cc = h * 32 + eh * 16 + lr;
#pragma unroll
        for (int j = 0; j < 4; ++j) {
          int pxl = pxl_base + j;
          float v = a[j];
          float sg = 1.f / (1.f + expf(-v));
          int byte = pxl * 512 + ((cc * 2) ^ ((pxl & 7) << 4));
          *(half_t*)(osm + byte) = (half_t)(v * sg * OSCALE);
        }
      }
    }
  }
  __syncthreads();

  // ---- phase 2: out = O @ Woh^T / OSCALE ----
  f32x4 acc[4][4];
#pragma unroll
  for (int i = 0; i < 4; ++i)
#pragma unroll
    for (int j = 0; j < 4; ++j) { f32x4 z = {0.f, 0.f, 0.f, 0.f}; acc[i][j] = z; }

  const half_t* wbase = Woh + ((size_t)(w * 64 + lr)) * 256 + lq * 8;
#pragma unroll
  for (int k0 = 0; k0 < 256; k0 += 32) {
    f16x8 afr[4], bfr[4];
#pragma unroll
    for (int mf = 0; mf < 4; ++mf)
      afr[mf] = *(const f16x8*)(wbase + (size_t)(mf * 16) * 256 + k0);
#pragma unroll
    for (int nf = 0; nf < 4; ++nf) {
      int r = nf * 16 + lr;
      bfr[nf] = *(const f16x8*)(osm + r * 512 + ((k0 * 2 + lq * 16) ^ ((r & 7) << 4)));
    }
#pragma unroll
    for (int mf = 0; mf < 4; ++mf)
#pragma unroll
      for (int nf = 0; nf < 4; ++nf)
        acc[mf][nf] = __builtin_amdgcn_mfma_f32_16x16x32_f16(afr[mf], bfr[nf], acc[mf][nf], 0, 0, 0);
  }

  // D[row=oc][col=px]; fp32 stores, 16 lanes consecutive px = 64B segments
#pragma unroll
  for (int mf = 0; mf < 4; ++mf) {
    int oc = w * 64 + mf * 16 + lq * 4;
#pragma unroll
    for (int nf = 0; nf < 4; ++nf) {
      float* dst = outp + ((size_t)(b * C + oc)) * HW + px0 + nf * 16 + lr;
#pragma unroll
      for (int j = 0; j < 4; ++j)
        dst[(size_t)j * HW] = acc[mf][nf][j] * (1.0f / OSCALE);
    }
  }
}

extern "C" void kernel_launch(void* const* d_in, const int* in_sizes, int n_in,
                              void* d_out, int out_size, void* d_ws, size_t ws_size,
                              hipStream_t stream) {
  const float* fmap = (const float*)d_in[0];
  const float* g    = (const float*)d_in[1];
  const float* wq1  = (const float*)d_in[2];
  const float* wq2  = (const float*)d_in[3];
  const float* wk1  = (const float*)d_in[4];
  const float* wk2  = (const float*)d_in[5];
  const float* wv1  = (const float*)d_in[6];
  const float* wv2  = (const float*)d_in[7];
  const float* wout = (const float*)d_in[8];
  float* out = (float*)d_out;
  char* ws = (char*)d_ws;

  const size_t SZ = (size_t)B * C * HW;
  const size_t Mi = (size_t)1 << 20;
  // layout (byte offsets), live ranges audited:
  half_t* Xh   = (half_t*)(ws);                  // [0,32Mi)    ln2 -> gemm
  half_t* Yh   = (half_t*)(ws + 32 * Mi);        // [32,128Mi)  Yq|Yk|Yv fp16
  half_t* Qh   = (half_t*)(ws + 128 * Mi);       // [128,160Mi) dwQ -> attn6b
  half_t* EK   = (half_t*)(ws);                  // [0,32Mi)    exp(k) fp16 (Xh dead)
  half_t* Vh   = (half_t*)out;                   // d_out as fp16 V until attn6b overwrites
  float*  part = (float*)(ws + 96 * Mi);         // [96,98Mi)   over dead Yv (full overwrite)
  float*  Sk   = (float*)(ws + 160 * Mi);        // 4KB — outside all tensor regions
  half_t* ctxh = (half_t*)(ws + 100 * Mi);       // 64KB over dead Yv (full overwrite)
  half_t* Wh   = (half_t*)(ws + 192 * Mi);
  half_t* Woh  = (half_t*)(ws + 192 * Mi + 512 * 1024);

  wcvt_all<<<dim3(1024), 256, 0, stream>>>(wq1, wk1, wv1, wout, Wh, Woh, Sk);

  ln2<<<dim3(HW / 64, B), 256, 0, stream>>>(fmap, g, Xh);

  gemm16r<<<dim3(HW / 128, 6, B), 512, 0, stream>>>(Xh, Wh, Yh);

  dw3x3_v<<<dim3(Hh / 16, C, B), 256, 0, stream>>>(Yh, wq2, Qh);               // Q fp16
  dw3x3_k<<<dim3(Hh / 16, C, B), 256, 0, stream>>>(Yh + SZ, wk2, EK, Sk);      // exp(K) + sum
  dw3x3_v<<<dim3(Hh / 16, C, B), 256, 0, stream>>>(Yh + 2 * SZ, wv2, Vh);      // V fp16

  ctx_mfma<<<dim3(HEADS * B, NSP), 256, 0, stream>>>(EK, Vh, part);
  ctxred<<<dim3(32), 256, 0, stream>>>(part, Sk, ctxh);

  attn6b<<<dim3(HW / 64, B), 256, 0, stream>>>(Qh, ctxh, Woh, out);
}

// Round 17
// 186.292 us; speedup vs baseline: 1.1947x; 1.0653x over previous
//
#include <hip/hip_runtime.h>
#include <cmath>

// LinearAttention round 17.
// vs r16: three dw3x3 launches fused into one dw3x3_all (grid.y = 3C,
// block-uniform tensor branch; K path keeps exp+atomic sum); attn6b gets
// explicit next-head ctx prefetch. GEMM (gemm16r) untouched — at its
// write-path plateau (~44us, 98MB mandatory fp16 writes @ ~2.8TB/s).

#define B 4
#define C 256
#define Hh 128
#define Wd 128
#define HW (Hh*Wd)
#define HEADS 8
#define HD 32
#define OSCALE 256.0f
#define NSP 16

typedef _Float16 half_t;
typedef _Float16 f16x8 __attribute__((ext_vector_type(8)));
typedef float f32x4 __attribute__((ext_vector_type(4)));

__device__ __forceinline__ void gload_lds16(const half_t* g, half_t* l) {
  __builtin_amdgcn_global_load_lds((const __attribute__((address_space(1))) void*)g,
                                   (__attribute__((address_space(3))) void*)l, 16, 0, 0);
}

// ---------------- all weights fp32 -> fp16 + zero Sk, one launch ----------------
__global__ __launch_bounds__(256) void wcvt_all(const float* __restrict__ wq1,
                                                const float* __restrict__ wk1,
                                                const float* __restrict__ wv1,
                                                const float* __restrict__ wout,
                                                half_t* __restrict__ Wh,
                                                half_t* __restrict__ Woh,
                                                float* __restrict__ Sk) {
  int i = blockIdx.x * 256 + threadIdx.x;  // grid 1024 -> 262144
  if (i < 65536) Wh[i] = (half_t)wq1[i];
  else if (i < 131072) Wh[i] = (half_t)wk1[i - 65536];
  else if (i < 196608) Wh[i] = (half_t)wv1[i - 131072];
  else Woh[i - 196608] = (half_t)wout[i - 196608];
  if (i < B * C) Sk[i] = 0.f;
}

// ---------------- channel LayerNorm -> X_h[b][pix][c] fp16 ----------------
__global__ __launch_bounds__(256) void ln2(const float* __restrict__ fmap,
                                           const float* __restrict__ g,
                                           half_t* __restrict__ Xh) {
  int b = blockIdx.y;
  int lane = threadIdx.x & 63;
  int gq = threadIdx.x >> 6;               // 0..3 channel group
  int px = blockIdx.x * 64 + lane;
  __shared__ float gs[C];
  __shared__ float sm1[4][64], sm2[4][64];
  gs[threadIdx.x] = g[threadIdx.x];
  const float* fp = fmap + ((size_t)b * C + gq * 64) * HW + px;
  float vbuf[64];
  float s = 0.f, s2 = 0.f;
#pragma unroll
  for (int j = 0; j < 64; ++j) {
    float v = fp[(size_t)j * HW];
    vbuf[j] = v;
    s += v; s2 = fmaf(v, v, s2);
  }
  sm1[gq][lane] = s; sm2[gq][lane] = s2;
  __syncthreads();
  float st = 0.f, st2 = 0.f;
#pragma unroll
  for (int q = 0; q < 4; ++q) { st += sm1[q][lane]; st2 += sm2[q][lane]; }
  float mean = st * (1.f / C);
  float var = st2 * (1.f / C) - mean * mean;
  float rstd = rsqrtf(var + 1e-5f);
  half_t* xp = Xh + ((size_t)b * HW + px) * 256 + gq * 64;
#pragma unroll
  for (int j0 = 0; j0 < 64; j0 += 8) {
    f16x8 v8;
#pragma unroll
    for (int jj = 0; jj < 8; ++jj)
      v8[jj] = (half_t)((vbuf[j0 + jj] - mean) * rstd * gs[gq * 64 + j0 + jj]);
    *(f16x8*)(xp + j0) = v8;
  }
}

// ---------------- fp16 MFMA GEMM: BK=32 ring-4, counted vmcnt (r16 proven) ----------------
__global__ __launch_bounds__(512) void gemm16r(const half_t* __restrict__ Xh,
                                               const half_t* __restrict__ Wh,
                                               half_t* __restrict__ Yh) {
  __shared__ __align__(16) char smem[65536];       // 4 ring slots / out tile
  const int tid = threadIdx.x;
  const int wave = tid >> 6, lane = tid & 63;
  const int lr = lane & 15, lq = lane >> 4;
  const int b = blockIdx.z;
  const int pix0 = blockIdx.x * 128;
  const int m0 = blockIdx.y * 128;
  const int wm = wave >> 1, wn = wave & 1;         // 4 m-waves x 2 px-waves

  const half_t* xb = Xh + ((size_t)b * HW + pix0) * 256;
  const half_t* wb = Wh + (size_t)m0 * 256;

  f32x4 acc[2][4];
#pragma unroll
  for (int i = 0; i < 2; ++i)
#pragma unroll
    for (int j = 0; j < 4; ++j) { f32x4 z = {0.f, 0.f, 0.f, 0.f}; acc[i][j] = z; }

#define STAGE(kt, s) do {                                                       \
    int r_ = tid >> 2, c_ = tid & 3;                                            \
    int cs_ = c_ ^ ((r_ >> 1) & 3);                                             \
    gload_lds16(xb + (size_t)r_ * 256 + (kt) * 32 + (cs_ << 3),                 \
                (half_t*)(smem + (s) * 16384) + tid * 8);                       \
    gload_lds16(wb + (size_t)r_ * 256 + (kt) * 32 + (cs_ << 3),                 \
                (half_t*)(smem + (s) * 16384 + 8192) + tid * 8);                \
  } while (0)

  STAGE(0, 0);
  STAGE(1, 1);

#pragma unroll
  for (int t = 0; t < 8; ++t) {
    if (t < 6) STAGE(t + 2, (t + 2) & 3);
    if (t < 6)       asm volatile("s_waitcnt vmcnt(4)" ::: "memory");
    else if (t == 6) asm volatile("s_waitcnt vmcnt(2)" ::: "memory");
    else             asm volatile("s_waitcnt vmcnt(0)" ::: "memory");
    __builtin_amdgcn_sched_barrier(0);
    __builtin_amdgcn_s_barrier();                  // all waves: tile t landed
    const char* slot = smem + (t & 3) * 16384;
    f16x8 afr[2], bfr[4];
#pragma unroll
    for (int mf = 0; mf < 2; ++mf) {
      int r = wm * 32 + mf * 16 + lr;
      afr[mf] = *(const f16x8*)(slot + 8192 + r * 64 + ((lq ^ ((r >> 1) & 3)) << 4));
    }
#pragma unroll
    for (int nf = 0; nf < 4; ++nf) {
      int r = wn * 64 + nf * 16 + lr;
      bfr[nf] = *(const f16x8*)(slot + r * 64 + ((lq ^ ((r >> 1) & 3)) << 4));
    }
#pragma unroll
    for (int mf = 0; mf < 2; ++mf)
#pragma unroll
      for (int nf = 0; nf < 4; ++nf)
        acc[mf][nf] = __builtin_amdgcn_mfma_f32_16x16x32_f16(afr[mf], bfr[nf], acc[mf][nf], 0, 0, 0);
  }
#undef STAGE
  asm volatile("s_waitcnt lgkmcnt(0)" ::: "memory");
  __builtin_amdgcn_sched_barrier(0);
  __builtin_amdgcn_s_barrier();                    // smem free for out tile

  // epilogue via swizzled LDS tile -> 256B row bursts
#pragma unroll
  for (int mf = 0; mf < 2; ++mf)
#pragma unroll
    for (int nf = 0; nf < 4; ++nf)
#pragma unroll
      for (int j = 0; j < 4; ++j) {
        int row = wm * 32 + mf * 16 + lq * 4 + j;
        int col = wn * 64 + nf * 16 + lr;
        int byte = row * 256 + ((col * 2) ^ ((row & 7) << 4));
        *(half_t*)(smem + byte) = (half_t)acc[mf][nf][j];
      }
  __syncthreads();
  half_t* dst_base = Yh + (size_t)(m0 >> 8) * ((size_t)B * C * HW)
                     + ((size_t)(b * C + (m0 & 255))) * HW + pix0;
#pragma unroll
  for (int it = 0; it < 4; ++it) {
    int i = it * 512 + tid;                 // 2048 chunks = 128 rows x 16
    int row = i >> 4, ch = i & 15;
    int src = row * 256 + ((ch * 16) ^ ((row & 7) << 4));
    *(f16x8*)(dst_base + (size_t)row * HW + ch * 8) = *(const f16x8*)(smem + src);
  }
}

// ---------------- fused depthwise 3x3 for Q, K(exp+sum), V — one launch ----------------
// grid (Hh/16, 3*C, B); block 256 = 16 rows x 16 col-groups. Branch is block-uniform.
__global__ __launch_bounds__(256) void dw3x3_all(const half_t* __restrict__ Yh,
                                                 const float* __restrict__ wq2,
                                                 const float* __restrict__ wk2,
                                                 const float* __restrict__ wv2,
                                                 half_t* __restrict__ Qh,
                                                 half_t* __restrict__ EK,
                                                 half_t* __restrict__ Vh,
                                                 float* __restrict__ Sk) {
  const size_t SZ = (size_t)B * C * HW;
  int ch = blockIdx.y;
  int ten = ch >> 8;                 // 0=Q, 1=K, 2=V
  int c = ch & 255;
  int b = blockIdx.z;
  int r = threadIdx.x >> 4;
  int j0 = (threadIdx.x & 15) * 8;
  int i = blockIdx.x * 16 + r;
  const half_t* plane = Yh + (size_t)ten * SZ + ((size_t)(b * C + c)) * HW;
  const float* W2 = (ten == 0) ? wq2 : (ten == 1) ? wk2 : wv2;
  float w[9];
#pragma unroll
  for (int k = 0; k < 9; ++k) w[k] = W2[c * 9 + k];
  float acc[8];
#pragma unroll
  for (int p = 0; p < 8; ++p) acc[p] = 0.f;
#pragma unroll
  for (int dr = 0; dr < 3; ++dr) {
    int ii = i + dr - 1;
    if (ii < 0 || ii >= Hh) continue;
    const half_t* rp = plane + ii * Wd + j0;
    f16x8 cv = *(const f16x8*)rp;
    float lv = (j0 > 0) ? (float)rp[-1] : 0.f;
    float rv = (j0 + 8 < Wd) ? (float)rp[8] : 0.f;
    float cf[8];
#pragma unroll
    for (int p = 0; p < 8; ++p) cf[p] = (float)cv[p];
    float w0 = w[dr * 3], w1 = w[dr * 3 + 1], w2v = w[dr * 3 + 2];
#pragma unroll
    for (int p = 0; p < 8; ++p) {
      float l = (p == 0) ? lv : cf[p - 1];
      float rr = (p == 7) ? rv : cf[p + 1];
      acc[p] = fmaf(w0, l, acc[p]);
      acc[p] = fmaf(w1, cf[p], acc[p]);
      acc[p] = fmaf(w2v, rr, acc[p]);
    }
  }
  size_t off = ((size_t)(b * C + c)) * HW + i * Wd + j0;
  if (ten == 1) {                    // K: exp + channel sum
    f16x8 o8;
    float local = 0.f;
#pragma unroll
    for (int p = 0; p < 8; ++p) {
      float e = expf(acc[p]);        // logits ~N(0,small): no max pass needed
      o8[p] = (half_t)e;
      local += e;
    }
    *(f16x8*)(EK + off) = o8;
    __shared__ float red[256];
    int t = threadIdx.x;
    red[t] = local; __syncthreads();
    for (int st = 128; st > 0; st >>= 1) {
      if (t < st) red[t] += red[t + st];
      __syncthreads();
    }
    if (t == 0) atomicAdd(&Sk[b * C + c], red[0]);
  } else {
    half_t* dst = (ten == 0) ? Qh : Vh;
    f16x8 o8;
#pragma unroll
    for (int p = 0; p < 8; ++p) o8[p] = (half_t)acc[p];
    *(f16x8*)(dst + off) = o8;
  }
}

// ---------------- ctx_raw = EK @ V^T per head, pure MFMA ----------------
__global__ __launch_bounds__(256) void ctx_mfma(const half_t* __restrict__ EK,
                                                const half_t* __restrict__ V,
                                                float* __restrict__ part) {
  int bh = blockIdx.x, sp = blockIdx.y;
  int wave = threadIdx.x >> 6, lane = threadIdx.x & 63;
  int lr = lane & 15, lq = lane >> 4;
  const size_t base = (size_t)bh * HD * HW;
  const half_t* ekp = EK + base + (size_t)lr * HW;
  const half_t* vp  = V  + base + (size_t)lr * HW;
  f32x4 a00 = {0.f,0.f,0.f,0.f}, a01 = a00, a10 = a00, a11 = a00;
  const int n0w = sp * 1024 + wave * 256 + lq * 8;
#pragma unroll
  for (int ks = 0; ks < 8; ++ks) {
    int n = n0w + ks * 32;
    f16x8 fa0 = *(const f16x8*)(ekp + n);
    f16x8 fa1 = *(const f16x8*)(ekp + (size_t)16 * HW + n);
    f16x8 fb0 = *(const f16x8*)(vp + n);
    f16x8 fb1 = *(const f16x8*)(vp + (size_t)16 * HW + n);
    a00 = __builtin_amdgcn_mfma_f32_16x16x32_f16(fa0, fb0, a00, 0, 0, 0);
    a01 = __builtin_amdgcn_mfma_f32_16x16x32_f16(fa0, fb1, a01, 0, 0, 0);
    a10 = __builtin_amdgcn_mfma_f32_16x16x32_f16(fa1, fb0, a10, 0, 0, 0);
    a11 = __builtin_amdgcn_mfma_f32_16x16x32_f16(fa1, fb1, a11, 0, 0, 0);
  }
  __shared__ float red[4][1024];
#pragma unroll
  for (int j = 0; j < 4; ++j) {
    int dlo = lq * 4 + j;
    red[wave][(dlo)      * 32 + lr]      = a00[j];
    red[wave][(dlo)      * 32 + 16 + lr] = a01[j];
    red[wave][(dlo + 16) * 32 + lr]      = a10[j];
    red[wave][(dlo + 16) * 32 + 16 + lr] = a11[j];
  }
  __syncthreads();
  float* pp = part + ((size_t)sp * 32 + bh) * 1024;
  for (int idx = threadIdx.x; idx < 1024; idx += 256)
    pp[idx] = red[0][idx] + red[1][idx] + red[2][idx] + red[3][idx];
}

// ---------------- reduce ctx partials, apply 1/S, emit fp16 TRANSPOSED [e][d] ----------------
__global__ __launch_bounds__(256) void ctxred(const float* __restrict__ part,
                                              const float* __restrict__ Sk,
                                              half_t* __restrict__ ctxh) {
  int bh = blockIdx.x;
  int t = threadIdx.x;
  for (int idx = t; idx < 1024; idx += 256) {
    int d = idx >> 5, e = idx & 31;
    float s = 0.f;
#pragma unroll
    for (int sp = 0; sp < NSP; ++sp) s += part[((size_t)sp * 32 + bh) * 1024 + idx];
    ctxh[(size_t)bh * 1024 + e * 32 + d] = (half_t)(s / Sk[bh * HD + d]);
  }
}

// ---------------- attn6b: P@ctx (MFMA) -> SiLU -> LDS O tile -> O@Wout^T -> fp32 out ----------------
// grid (HW/64, B), block 256 = 4 waves; per-head ctx loads with next-head prefetch.
__global__ __launch_bounds__(256) void attn6b(const half_t* __restrict__ Qh,
                                              const half_t* __restrict__ ctxh,
                                              const half_t* __restrict__ Woh,
                                              float* __restrict__ outp) {
  const int b = blockIdx.y;
  const int lane = threadIdx.x & 63;
  const int w = threadIdx.x >> 6;
  const int lr = lane & 15, lq = lane >> 4;
  const int px0 = blockIdx.x * 64;
  const int px = px0 + w * 16 + lr;                   // phase-1 A-row pixel
  __shared__ __align__(16) char osm[64 * 512];        // 32KB O tile [px][c] fp16 swizzled

  // ---- phase 1: O = silu(softmax(q) @ ctx) * OSCALE ----
  {
    const int pxl_base = w * 16 + lq * 4;
    const half_t* cb = ctxh + ((size_t)b * HEADS) * 1024;
    f16x8 cf0 = *(const f16x8*)(cb + (lr)      * 32 + lq * 8);
    f16x8 cf1 = *(const f16x8*)(cb + (16 + lr) * 32 + lq * 8);
#pragma unroll
    for (int h = 0; h < HEADS; ++h) {
      f16x8 nf0, nf1;
      if (h < HEADS - 1) {                            // prefetch next head's frags
        const half_t* nb = cb + (size_t)(h + 1) * 1024;
        nf0 = *(const f16x8*)(nb + (lr)      * 32 + lq * 8);
        nf1 = *(const f16x8*)(nb + (16 + lr) * 32 + lq * 8);
      }
      const half_t* qp = Qh + ((size_t)(b * C + h * HD + lq * 8)) * HW + px;
      float ev[8];
      float psum = 0.f;
#pragma unroll
      for (int j = 0; j < 8; ++j) {
        ev[j] = expf((float)qp[(size_t)j * HW]);      // no max pass: logits bounded
        psum += ev[j];
      }
      float s = psum;
      s += __shfl_xor(s, 16, 64);
      s += __shfl_xor(s, 32, 64);
      float inv = 0.1767766952966369f / s;            // 32^-0.5 / s
      f16x8 pa;
#pragma unroll
      for (int j = 0; j < 8; ++j) pa[j] = (half_t)(ev[j] * inv);

      f32x4 z = {0.f, 0.f, 0.f, 0.f};
      f32x4 a0 = __builtin_amdgcn_mfma_f32_16x16x32_f16(pa, cf0, z, 0, 0, 0);
      f32x4 a1 = __builtin_amdgcn_mfma_f32_16x16x32_f16(pa, cf1, z, 0, 0, 0);
#pragma unroll
      for (int eh = 0; eh < 2; ++eh) {
        f32x4 a = eh ? a1 : a0;
        int cc = h * 32 + eh * 16 + lr;
#pragma unroll
        for (int j = 0; j < 4; ++j) {
          int pxl = pxl_base + j;
          float v = a[j];
          float sg = 1.f / (1.f + expf(-v));
          int byte = pxl * 512 + ((cc * 2) ^ ((pxl & 7) << 4));
          *(half_t*)(osm + byte) = (half_t)(v * sg * OSCALE);
        }
      }
      cf0 = nf0; cf1 = nf1;
    }
  }
  __syncthreads();

  // ---- phase 2: out = O @ Woh^T / OSCALE ----
  f32x4 acc[4][4];
#pragma unroll
  for (int i = 0; i < 4; ++i)
#pragma unroll
    for (int j = 0; j < 4; ++j) { f32x4 z = {0.f, 0.f, 0.f, 0.f}; acc[i][j] = z; }

  const half_t* wbase = Woh + ((size_t)(w * 64 + lr)) * 256 + lq * 8;
#pragma unroll
  for (int k0 = 0; k0 < 256; k0 += 32) {
    f16x8 afr[4], bfr[4];
#pragma unroll
    for (int mf = 0; mf < 4; ++mf)
      afr[mf] = *(const f16x8*)(wbase + (size_t)(mf * 16) * 256 + k0);
#pragma unroll
    for (int nf = 0; nf < 4; ++nf) {
      int r = nf * 16 + lr;
      bfr[nf] = *(const f16x8*)(osm + r * 512 + ((k0 * 2 + lq * 16) ^ ((r & 7) << 4)));
    }
#pragma unroll
    for (int mf = 0; mf < 4; ++mf)
#pragma unroll
      for (int nf = 0; nf < 4; ++nf)
        acc[mf][nf] = __builtin_amdgcn_mfma_f32_16x16x32_f16(afr[mf], bfr[nf], acc[mf][nf], 0, 0, 0);
  }

  // D[row=oc][col=px]; fp32 stores, 16 lanes consecutive px = 64B segments
#pragma unroll
  for (int mf = 0; mf < 4; ++mf) {
    int oc = w * 64 + mf * 16 + lq * 4;
#pragma unroll
    for (int nf = 0; nf < 4; ++nf) {
      float* dst = outp + ((size_t)(b * C + oc)) * HW + px0 + nf * 16 + lr;
#pragma unroll
      for (int j = 0; j < 4; ++j)
        dst[(size_t)j * HW] = acc[mf][nf][j] * (1.0f / OSCALE);
    }
  }
}

extern "C" void kernel_launch(void* const* d_in, const int* in_sizes, int n_in,
                              void* d_out, int out_size, void* d_ws, size_t ws_size,
                              hipStream_t stream) {
  const float* fmap = (const float*)d_in[0];
  const float* g    = (const float*)d_in[1];
  const float* wq1  = (const float*)d_in[2];
  const float* wq2  = (const float*)d_in[3];
  const float* wk1  = (const float*)d_in[4];
  const float* wk2  = (const float*)d_in[5];
  const float* wv1  = (const float*)d_in[6];
  const float* wv2  = (const float*)d_in[7];
  const float* wout = (const float*)d_in[8];
  float* out = (float*)d_out;
  char* ws = (char*)d_ws;

  const size_t SZ = (size_t)B * C * HW;
  const size_t Mi = (size_t)1 << 20;
  // layout (byte offsets), live ranges audited:
  half_t* Xh   = (half_t*)(ws);                  // [0,32Mi)    ln2 -> gemm
  half_t* Yh   = (half_t*)(ws + 32 * Mi);        // [32,128Mi)  Yq|Yk|Yv fp16
  half_t* Qh   = (half_t*)(ws + 128 * Mi);       // [128,160Mi) dw -> attn6b
  half_t* EK   = (half_t*)(ws);                  // [0,32Mi)    exp(k) fp16 (Xh dead)
  half_t* Vh   = (half_t*)out;                   // d_out as fp16 V until attn6b overwrites
  float*  part = (float*)(ws + 96 * Mi);         // [96,98Mi)   over dead Yv (full overwrite)
  float*  Sk   = (float*)(ws + 160 * Mi);        // 4KB — outside all tensor regions
  half_t* ctxh = (half_t*)(ws + 100 * Mi);       // 64KB over dead Yv (full overwrite)
  half_t* Wh   = (half_t*)(ws + 192 * Mi);
  half_t* Woh  = (half_t*)(ws + 192 * Mi + 512 * 1024);

  wcvt_all<<<dim3(1024), 256, 0, stream>>>(wq1, wk1, wv1, wout, Wh, Woh, Sk);

  ln2<<<dim3(HW / 64, B), 256, 0, stream>>>(fmap, g, Xh);

  gemm16r<<<dim3(HW / 128, 6, B), 512, 0, stream>>>(Xh, Wh, Yh);

  dw3x3_all<<<dim3(Hh / 16, 3 * C, B), 256, 0, stream>>>(Yh, wq2, wk2, wv2,
                                                         Qh, EK, Vh, Sk);

  ctx_mfma<<<dim3(HEADS * B, NSP), 256, 0, stream>>>(EK, Vh, part);
  ctxred<<<dim3(32), 256, 0, stream>>>(part, Sk, ctxh);

  attn6b<<<dim3(HW / 64, B), 256, 0, stream>>>(Qh, ctxh, Woh, out);
}

// Round 18
// 180.578 us; speedup vs baseline: 1.2326x; 1.0316x over previous
//
#include <hip/hip_runtime.h>
#include <cmath>

// LinearAttention round 18.
// vs r17: dw3x3_all rewritten in packed fp16 (v_pk_fma_f16) — conv math on
// f16x8 vectors, no f32 cvt on Q/V paths. r17 profile: 61us, VALUBusy 44%,
// HBM 32% -> VALU-cost-bound; packed math halves the ALU work.

#define B 4
#define C 256
#define Hh 128
#define Wd 128
#define HW (Hh*Wd)
#define HEADS 8
#define HD 32
#define OSCALE 256.0f
#define NSP 16

typedef _Float16 half_t;
typedef _Float16 f16x8 __attribute__((ext_vector_type(8)));
typedef float f32x4 __attribute__((ext_vector_type(4)));

__device__ __forceinline__ void gload_lds16(const half_t* g, half_t* l) {
  __builtin_amdgcn_global_load_lds((const __attribute__((address_space(1))) void*)g,
                                   (__attribute__((address_space(3))) void*)l, 16, 0, 0);
}

// ---------------- all weights fp32 -> fp16 + zero Sk, one launch ----------------
__global__ __launch_bounds__(256) void wcvt_all(const float* __restrict__ wq1,
                                                const float* __restrict__ wk1,
                                                const float* __restrict__ wv1,
                                                const float* __restrict__ wout,
                                                half_t* __restrict__ Wh,
                                                half_t* __restrict__ Woh,
                                                float* __restrict__ Sk) {
  int i = blockIdx.x * 256 + threadIdx.x;  // grid 1024 -> 262144
  if (i < 65536) Wh[i] = (half_t)wq1[i];
  else if (i < 131072) Wh[i] = (half_t)wk1[i - 65536];
  else if (i < 196608) Wh[i] = (half_t)wv1[i - 131072];
  else Woh[i - 196608] = (half_t)wout[i - 196608];
  if (i < B * C) Sk[i] = 0.f;
}

// ---------------- channel LayerNorm -> X_h[b][pix][c] fp16 ----------------
__global__ __launch_bounds__(256) void ln2(const float* __restrict__ fmap,
                                           const float* __restrict__ g,
                                           half_t* __restrict__ Xh) {
  int b = blockIdx.y;
  int lane = threadIdx.x & 63;
  int gq = threadIdx.x >> 6;               // 0..3 channel group
  int px = blockIdx.x * 64 + lane;
  __shared__ float gs[C];
  __shared__ float sm1[4][64], sm2[4][64];
  gs[threadIdx.x] = g[threadIdx.x];
  const float* fp = fmap + ((size_t)b * C + gq * 64) * HW + px;
  float vbuf[64];
  float s = 0.f, s2 = 0.f;
#pragma unroll
  for (int j = 0; j < 64; ++j) {
    float v = fp[(size_t)j * HW];
    vbuf[j] = v;
    s += v; s2 = fmaf(v, v, s2);
  }
  sm1[gq][lane] = s; sm2[gq][lane] = s2;
  __syncthreads();
  float st = 0.f, st2 = 0.f;
#pragma unroll
  for (int q = 0; q < 4; ++q) { st += sm1[q][lane]; st2 += sm2[q][lane]; }
  float mean = st * (1.f / C);
  float var = st2 * (1.f / C) - mean * mean;
  float rstd = rsqrtf(var + 1e-5f);
  half_t* xp = Xh + ((size_t)b * HW + px) * 256 + gq * 64;
#pragma unroll
  for (int j0 = 0; j0 < 64; j0 += 8) {
    f16x8 v8;
#pragma unroll
    for (int jj = 0; jj < 8; ++jj)
      v8[jj] = (half_t)((vbuf[j0 + jj] - mean) * rstd * gs[gq * 64 + j0 + jj]);
    *(f16x8*)(xp + j0) = v8;
  }
}

// ---------------- fp16 MFMA GEMM: BK=32 ring-4, counted vmcnt (r16 proven) ----------------
__global__ __launch_bounds__(512) void gemm16r(const half_t* __restrict__ Xh,
                                               const half_t* __restrict__ Wh,
                                               half_t* __restrict__ Yh) {
  __shared__ __align__(16) char smem[65536];       // 4 ring slots / out tile
  const int tid = threadIdx.x;
  const int wave = tid >> 6, lane = tid & 63;
  const int lr = lane & 15, lq = lane >> 4;
  const int b = blockIdx.z;
  const int pix0 = blockIdx.x * 128;
  const int m0 = blockIdx.y * 128;
  const int wm = wave >> 1, wn = wave & 1;         // 4 m-waves x 2 px-waves

  const half_t* xb = Xh + ((size_t)b * HW + pix0) * 256;
  const half_t* wb = Wh + (size_t)m0 * 256;

  f32x4 acc[2][4];
#pragma unroll
  for (int i = 0; i < 2; ++i)
#pragma unroll
    for (int j = 0; j < 4; ++j) { f32x4 z = {0.f, 0.f, 0.f, 0.f}; acc[i][j] = z; }

#define STAGE(kt, s) do {                                                       \
    int r_ = tid >> 2, c_ = tid & 3;                                            \
    int cs_ = c_ ^ ((r_ >> 1) & 3);                                             \
    gload_lds16(xb + (size_t)r_ * 256 + (kt) * 32 + (cs_ << 3),                 \
                (half_t*)(smem + (s) * 16384) + tid * 8);                       \
    gload_lds16(wb + (size_t)r_ * 256 + (kt) * 32 + (cs_ << 3),                 \
                (half_t*)(smem + (s) * 16384 + 8192) + tid * 8);                \
  } while (0)

  STAGE(0, 0);
  STAGE(1, 1);

#pragma unroll
  for (int t = 0; t < 8; ++t) {
    if (t < 6) STAGE(t + 2, (t + 2) & 3);
    if (t < 6)       asm volatile("s_waitcnt vmcnt(4)" ::: "memory");
    else if (t == 6) asm volatile("s_waitcnt vmcnt(2)" ::: "memory");
    else             asm volatile("s_waitcnt vmcnt(0)" ::: "memory");
    __builtin_amdgcn_sched_barrier(0);
    __builtin_amdgcn_s_barrier();                  // all waves: tile t landed
    const char* slot = smem + (t & 3) * 16384;
    f16x8 afr[2], bfr[4];
#pragma unroll
    for (int mf = 0; mf < 2; ++mf) {
      int r = wm * 32 + mf * 16 + lr;
      afr[mf] = *(const f16x8*)(slot + 8192 + r * 64 + ((lq ^ ((r >> 1) & 3)) << 4));
    }
#pragma unroll
    for (int nf = 0; nf < 4; ++nf) {
      int r = wn * 64 + nf * 16 + lr;
      bfr[nf] = *(const f16x8*)(slot + r * 64 + ((lq ^ ((r >> 1) & 3)) << 4));
    }
#pragma unroll
    for (int mf = 0; mf < 2; ++mf)
#pragma unroll
      for (int nf = 0; nf < 4; ++nf)
        acc[mf][nf] = __builtin_amdgcn_mfma_f32_16x16x32_f16(afr[mf], bfr[nf], acc[mf][nf], 0, 0, 0);
  }
#undef STAGE
  asm volatile("s_waitcnt lgkmcnt(0)" ::: "memory");
  __builtin_amdgcn_sched_barrier(0);
  __builtin_amdgcn_s_barrier();                    // smem free for out tile

  // epilogue via swizzled LDS tile -> 256B row bursts
#pragma unroll
  for (int mf = 0; mf < 2; ++mf)
#pragma unroll
    for (int nf = 0; nf < 4; ++nf)
#pragma unroll
      for (int j = 0; j < 4; ++j) {
        int row = wm * 32 + mf * 16 + lq * 4 + j;
        int col = wn * 64 + nf * 16 + lr;
        int byte = row * 256 + ((col * 2) ^ ((row & 7) << 4));
        *(half_t*)(smem + byte) = (half_t)acc[mf][nf][j];
      }
  __syncthreads();
  half_t* dst_base = Yh + (size_t)(m0 >> 8) * ((size_t)B * C * HW)
                     + ((size_t)(b * C + (m0 & 255))) * HW + pix0;
#pragma unroll
  for (int it = 0; it < 4; ++it) {
    int i = it * 512 + tid;                 // 2048 chunks = 128 rows x 16
    int row = i >> 4, ch = i & 15;
    int src = row * 256 + ((ch * 16) ^ ((row & 7) << 4));
    *(f16x8*)(dst_base + (size_t)row * HW + ch * 8) = *(const f16x8*)(smem + src);
  }
}

// ---------------- fused depthwise 3x3 (packed fp16 math) for Q, K(exp+sum), V ----------------
// grid (Hh/16, 3*C, B); block 256 = 16 rows x 16 col-groups. Branch is block-uniform.
__global__ __launch_bounds__(256) void dw3x3_all(const half_t* __restrict__ Yh,
                                                 const float* __restrict__ wq2,
                                                 const float* __restrict__ wk2,
                                                 const float* __restrict__ wv2,
                                                 half_t* __restrict__ Qh,
                                                 half_t* __restrict__ EK,
                                                 half_t* __restrict__ Vh,
                                                 float* __restrict__ Sk) {
  const size_t SZ = (size_t)B * C * HW;
  int ch = blockIdx.y;
  int ten = ch >> 8;                 // 0=Q, 1=K, 2=V
  int c = ch & 255;
  int b = blockIdx.z;
  int r = threadIdx.x >> 4;
  int j0 = (threadIdx.x & 15) * 8;
  int i = blockIdx.x * 16 + r;
  const half_t* plane = Yh + (size_t)ten * SZ + ((size_t)(b * C + c)) * HW;
  const float* W2 = (ten == 0) ? wq2 : (ten == 1) ? wk2 : wv2;
  half_t wh[9];
#pragma unroll
  for (int k = 0; k < 9; ++k) wh[k] = (half_t)W2[c * 9 + k];
  f16x8 acc8 = {0, 0, 0, 0, 0, 0, 0, 0};
#pragma unroll
  for (int dr = 0; dr < 3; ++dr) {
    int ii = i + dr - 1;
    if (ii < 0 || ii >= Hh) continue;
    const half_t* rp = plane + ii * Wd + j0;
    f16x8 cv = *(const f16x8*)rp;
    half_t lv = (j0 > 0) ? rp[-1] : (half_t)0.f;
    half_t rv = (j0 + 8 < Wd) ? rp[8] : (half_t)0.f;
    f16x8 lsh = __builtin_shufflevector(cv, cv, 0, 0, 1, 2, 3, 4, 5, 6);
    lsh[0] = lv;
    f16x8 rsh = __builtin_shufflevector(cv, cv, 1, 2, 3, 4, 5, 6, 7, 7);
    rsh[7] = rv;
    acc8 += lsh * wh[dr * 3] + cv * wh[dr * 3 + 1] + rsh * wh[dr * 3 + 2];
  }
  size_t off = ((size_t)(b * C + c)) * HW + i * Wd + j0;
  if (ten == 1) {                    // K: exp + channel sum (fp32 exp)
    f16x8 o8;
    float local = 0.f;
#pragma unroll
    for (int p = 0; p < 8; ++p) {
      float e = expf((float)acc8[p]);  // logits ~N(0,small): no max pass needed
      o8[p] = (half_t)e;
      local += e;
    }
    *(f16x8*)(EK + off) = o8;
    __shared__ float red[256];
    int t = threadIdx.x;
    red[t] = local; __syncthreads();
    for (int st = 128; st > 0; st >>= 1) {
      if (t < st) red[t] += red[t + st];
      __syncthreads();
    }
    if (t == 0) atomicAdd(&Sk[b * C + c], red[0]);
  } else {
    half_t* dst = (ten == 0) ? Qh : Vh;
    *(f16x8*)(dst + off) = acc8;
  }
}

// ---------------- ctx_raw = EK @ V^T per head, pure MFMA ----------------
__global__ __launch_bounds__(256) void ctx_mfma(const half_t* __restrict__ EK,
                                                const half_t* __restrict__ V,
                                                float* __restrict__ part) {
  int bh = blockIdx.x, sp = blockIdx.y;
  int wave = threadIdx.x >> 6, lane = threadIdx.x & 63;
  int lr = lane & 15, lq = lane >> 4;
  const size_t base = (size_t)bh * HD * HW;
  const half_t* ekp = EK + base + (size_t)lr * HW;
  const half_t* vp  = V  + base + (size_t)lr * HW;
  f32x4 a00 = {0.f,0.f,0.f,0.f}, a01 = a00, a10 = a00, a11 = a00;
  const int n0w = sp * 1024 + wave * 256 + lq * 8;
#pragma unroll
  for (int ks = 0; ks < 8; ++ks) {
    int n = n0w + ks * 32;
    f16x8 fa0 = *(const f16x8*)(ekp + n);
    f16x8 fa1 = *(const f16x8*)(ekp + (size_t)16 * HW + n);
    f16x8 fb0 = *(const f16x8*)(vp + n);
    f16x8 fb1 = *(const f16x8*)(vp + (size_t)16 * HW + n);
    a00 = __builtin_amdgcn_mfma_f32_16x16x32_f16(fa0, fb0, a00, 0, 0, 0);
    a01 = __builtin_amdgcn_mfma_f32_16x16x32_f16(fa0, fb1, a01, 0, 0, 0);
    a10 = __builtin_amdgcn_mfma_f32_16x16x32_f16(fa1, fb0, a10, 0, 0, 0);
    a11 = __builtin_amdgcn_mfma_f32_16x16x32_f16(fa1, fb1, a11, 0, 0, 0);
  }
  __shared__ float red[4][1024];
#pragma unroll
  for (int j = 0; j < 4; ++j) {
    int dlo = lq * 4 + j;
    red[wave][(dlo)      * 32 + lr]      = a00[j];
    red[wave][(dlo)      * 32 + 16 + lr] = a01[j];
    red[wave][(dlo + 16) * 32 + lr]      = a10[j];
    red[wave][(dlo + 16) * 32 + 16 + lr] = a11[j];
  }
  __syncthreads();
  float* pp = part + ((size_t)sp * 32 + bh) * 1024;
  for (int idx = threadIdx.x; idx < 1024; idx += 256)
    pp[idx] = red[0][idx] + red[1][idx] + red[2][idx] + red[3][idx];
}

// ---------------- reduce ctx partials, apply 1/S, emit fp16 TRANSPOSED [e][d] ----------------
__global__ __launch_bounds__(256) void ctxred(const float* __restrict__ part,
                                              const float* __restrict__ Sk,
                                              half_t* __restrict__ ctxh) {
  int bh = blockIdx.x;
  int t = threadIdx.x;
  for (int idx = t; idx < 1024; idx += 256) {
    int d = idx >> 5, e = idx & 31;
    float s = 0.f;
#pragma unroll
    for (int sp = 0; sp < NSP; ++sp) s += part[((size_t)sp * 32 + bh) * 1024 + idx];
    ctxh[(size_t)bh * 1024 + e * 32 + d] = (half_t)(s / Sk[bh * HD + d]);
  }
}

// ---------------- attn6b: P@ctx (MFMA) -> SiLU -> LDS O tile -> O@Wout^T -> fp32 out ----------------
__global__ __launch_bounds__(256) void attn6b(const half_t* __restrict__ Qh,
                                              const half_t* __restrict__ ctxh,
                                              const half_t* __restrict__ Woh,
                                              float* __restrict__ outp) {
  const int b = blockIdx.y;
  const int lane = threadIdx.x & 63;
  const int w = threadIdx.x >> 6;
  const int lr = lane & 15, lq = lane >> 4;
  const int px0 = blockIdx.x * 64;
  const int px = px0 + w * 16 + lr;                   // phase-1 A-row pixel
  __shared__ __align__(16) char osm[64 * 512];        // 32KB O tile [px][c] fp16 swizzled

  // ---- phase 1: O = silu(softmax(q) @ ctx) * OSCALE ----
  {
    const int pxl_base = w * 16 + lq * 4;
    const half_t* cb = ctxh + ((size_t)b * HEADS) * 1024;
    f16x8 cf0 = *(const f16x8*)(cb + (lr)      * 32 + lq * 8);
    f16x8 cf1 = *(const f16x8*)(cb + (16 + lr) * 32 + lq * 8);
#pragma unroll
    for (int h = 0; h < HEADS; ++h) {
      f16x8 nf0, nf1;
      if (h < HEADS - 1) {                            // prefetch next head's frags
        const half_t* nb = cb + (size_t)(h + 1) * 1024;
        nf0 = *(const f16x8*)(nb + (lr)      * 32 + lq * 8);
        nf1 = *(const f16x8*)(nb + (16 + lr) * 32 + lq * 8);
      }
      const half_t* qp = Qh + ((size_t)(b * C + h * HD + lq * 8)) * HW + px;
      float ev[8];
      float psum = 0.f;
#pragma unroll
      for (int j = 0; j < 8; ++j) {
        ev[j] = expf((float)qp[(size_t)j * HW]);      // no max pass: logits bounded
        psum += ev[j];
      }
      float s = psum;
      s += __shfl_xor(s, 16, 64);
      s += __shfl_xor(s, 32, 64);
      float inv = 0.1767766952966369f / s;            // 32^-0.5 / s
      f16x8 pa;
#pragma unroll
      for (int j = 0; j < 8; ++j) pa[j] = (half_t)(ev[j] * inv);

      f32x4 z = {0.f, 0.f, 0.f, 0.f};
      f32x4 a0 = __builtin_amdgcn_mfma_f32_16x16x32_f16(pa, cf0, z, 0, 0, 0);
      f32x4 a1 = __builtin_amdgcn_mfma_f32_16x16x32_f16(pa, cf1, z, 0, 0, 0);
#pragma unroll
      for (int eh = 0; eh < 2; ++eh) {
        f32x4 a = eh ? a1 : a0;
        int cc = h * 32 + eh * 16 + lr;
#pragma unroll
        for (int j = 0; j < 4; ++j) {
          int pxl = pxl_base + j;
          float v = a[j];
          float sg = 1.f / (1.f + expf(-v));
          int byte = pxl * 512 + ((cc * 2) ^ ((pxl & 7) << 4));
          *(half_t*)(osm + byte) = (half_t)(v * sg * OSCALE);
        }
      }
      cf0 = nf0; cf1 = nf1;
    }
  }
  __syncthreads();

  // ---- phase 2: out = O @ Woh^T / OSCALE ----
  f32x4 acc[4][4];
#pragma unroll
  for (int i = 0; i < 4; ++i)
#pragma unroll
    for (int j = 0; j < 4; ++j) { f32x4 z = {0.f, 0.f, 0.f, 0.f}; acc[i][j] = z; }

  const half_t* wbase = Woh + ((size_t)(w * 64 + lr)) * 256 + lq * 8;
#pragma unroll
  for (int k0 = 0; k0 < 256; k0 += 32) {
    f16x8 afr[4], bfr[4];
#pragma unroll
    for (int mf = 0; mf < 4; ++mf)
      afr[mf] = *(const f16x8*)(wbase + (size_t)(mf * 16) * 256 + k0);
#pragma unroll
    for (int nf = 0; nf < 4; ++nf) {
      int r = nf * 16 + lr;
      bfr[nf] = *(const f16x8*)(osm + r * 512 + ((k0 * 2 + lq * 16) ^ ((r & 7) << 4)));
    }
#pragma unroll
    for (int mf = 0; mf < 4; ++mf)
#pragma unroll
      for (int nf = 0; nf < 4; ++nf)
        acc[mf][nf] = __builtin_amdgcn_mfma_f32_16x16x32_f16(afr[mf], bfr[nf], acc[mf][nf], 0, 0, 0);
  }

  // D[row=oc][col=px]; fp32 stores, 16 lanes consecutive px = 64B segments
#pragma unroll
  for (int mf = 0; mf < 4; ++mf) {
    int oc = w * 64 + mf * 16 + lq * 4;
#pragma unroll
    for (int nf = 0; nf < 4; ++nf) {
      float* dst = outp + ((size_t)(b * C + oc)) * HW + px0 + nf * 16 + lr;
#pragma unroll
      for (int j = 0; j < 4; ++j)
        dst[(size_t)j * HW] = acc[mf][nf][j] * (1.0f / OSCALE);
    }
  }
}

extern "C" void kernel_launch(void* const* d_in, const int* in_sizes, int n_in,
                              void* d_out, int out_size, void* d_ws, size_t ws_size,
                              hipStream_t stream) {
  const float* fmap = (const float*)d_in[0];
  const float* g    = (const float*)d_in[1];
  const float* wq1  = (const float*)d_in[2];
  const float* wq2  = (const float*)d_in[3];
  const float* wk1  = (const float*)d_in[4];
  const float* wk2  = (const float*)d_in[5];
  const float* wv1  = (const float*)d_in[6];
  const float* wv2  = (const float*)d_in[7];
  const float* wout = (const float*)d_in[8];
  float* out = (float*)d_out;
  char* ws = (char*)d_ws;

  const size_t SZ = (size_t)B * C * HW;
  const size_t Mi = (size_t)1 << 20;
  // layout (byte offsets), live ranges audited:
  half_t* Xh   = (half_t*)(ws);                  // [0,32Mi)    ln2 -> gemm
  half_t* Yh   = (half_t*)(ws + 32 * Mi);        // [32,128Mi)  Yq|Yk|Yv fp16
  half_t* Qh   = (half_t*)(ws + 128 * Mi);       // [128,160Mi) dw -> attn6b
  half_t* EK   = (half_t*)(ws);                  // [0,32Mi)    exp(k) fp16 (Xh dead)
  half_t* Vh   = (half_t*)out;                   // d_out as fp16 V until attn6b overwrites
  float*  part = (float*)(ws + 96 * Mi);         // [96,98Mi)   over dead Yv (full overwrite)
  float*  Sk   = (float*)(ws + 160 * Mi);        // 4KB — outside all tensor regions
  half_t* ctxh = (half_t*)(ws + 100 * Mi);       // 64KB over dead Yv (full overwrite)
  half_t* Wh   = (half_t*)(ws + 192 * Mi);
  half_t* Woh  = (half_t*)(ws + 192 * Mi + 512 * 1024);

  wcvt_all<<<dim3(1024), 256, 0, stream>>>(wq1, wk1, wv1, wout, Wh, Woh, Sk);

  ln2<<<dim3(HW / 64, B), 256, 0, stream>>>(fmap, g, Xh);

  gemm16r<<<dim3(HW / 128, 6, B), 512, 0, stream>>>(Xh, Wh, Yh);

  dw3x3_all<<<dim3(Hh / 16, 3 * C, B), 256, 0, stream>>>(Yh, wq2, wk2, wv2,
                                                         Qh, EK, Vh, Sk);

  ctx_mfma<<<dim3(HEADS * B, NSP), 256, 0, stream>>>(EK, Vh, part);
  ctxred<<<dim3(32), 256, 0, stream>>>(part, Sk, ctxh);

  attn6b<<<dim3(HW / 64, B), 256, 0, stream>>>(Qh, ctxh, Woh, out);
}

// Round 19
// 169.404 us; speedup vs baseline: 1.3139x; 1.0660x over previous
//
#include <hip/hip_runtime.h>
#include <cmath>

// LinearAttention round 19.
// vs r18: dw3x3_all horizontal shifts redone in dword form — uint4 row loads,
// 5x v_alignbit_b32 for the +-1-element shifted vectors (shared interior
// dwords), halos via __shfl from the neighbor lane (no scalar global loads).
// Mem insts 10->4/thread, VALU ~3x down. Everything else frozen.

#define B 4
#define C 256
#define Hh 128
#define Wd 128
#define HW (Hh*Wd)
#define HEADS 8
#define HD 32
#define OSCALE 256.0f
#define NSP 16

typedef _Float16 half_t;
typedef _Float16 f16x8 __attribute__((ext_vector_type(8)));
typedef float f32x4 __attribute__((ext_vector_type(4)));

__device__ __forceinline__ void gload_lds16(const half_t* g, half_t* l) {
  __builtin_amdgcn_global_load_lds((const __attribute__((address_space(1))) void*)g,
                                   (__attribute__((address_space(3))) void*)l, 16, 0, 0);
}

// ---------------- all weights fp32 -> fp16 + zero Sk, one launch ----------------
__global__ __launch_bounds__(256) void wcvt_all(const float* __restrict__ wq1,
                                                const float* __restrict__ wk1,
                                                const float* __restrict__ wv1,
                                                const float* __restrict__ wout,
                                                half_t* __restrict__ Wh,
                                                half_t* __restrict__ Woh,
                                                float* __restrict__ Sk) {
  int i = blockIdx.x * 256 + threadIdx.x;  // grid 1024 -> 262144
  if (i < 65536) Wh[i] = (half_t)wq1[i];
  else if (i < 131072) Wh[i] = (half_t)wk1[i - 65536];
  else if (i < 196608) Wh[i] = (half_t)wv1[i - 131072];
  else Woh[i - 196608] = (half_t)wout[i - 196608];
  if (i < B * C) Sk[i] = 0.f;
}

// ---------------- channel LayerNorm -> X_h[b][pix][c] fp16 ----------------
__global__ __launch_bounds__(256) void ln2(const float* __restrict__ fmap,
                                           const float* __restrict__ g,
                                           half_t* __restrict__ Xh) {
  int b = blockIdx.y;
  int lane = threadIdx.x & 63;
  int gq = threadIdx.x >> 6;               // 0..3 channel group
  int px = blockIdx.x * 64 + lane;
  __shared__ float gs[C];
  __shared__ float sm1[4][64], sm2[4][64];
  gs[threadIdx.x] = g[threadIdx.x];
  const float* fp = fmap + ((size_t)b * C + gq * 64) * HW + px;
  float vbuf[64];
  float s = 0.f, s2 = 0.f;
#pragma unroll
  for (int j = 0; j < 64; ++j) {
    float v = fp[(size_t)j * HW];
    vbuf[j] = v;
    s += v; s2 = fmaf(v, v, s2);
  }
  sm1[gq][lane] = s; sm2[gq][lane] = s2;
  __syncthreads();
  float st = 0.f, st2 = 0.f;
#pragma unroll
  for (int q = 0; q < 4; ++q) { st += sm1[q][lane]; st2 += sm2[q][lane]; }
  float mean = st * (1.f / C);
  float var = st2 * (1.f / C) - mean * mean;
  float rstd = rsqrtf(var + 1e-5f);
  half_t* xp = Xh + ((size_t)b * HW + px) * 256 + gq * 64;
#pragma unroll
  for (int j0 = 0; j0 < 64; j0 += 8) {
    f16x8 v8;
#pragma unroll
    for (int jj = 0; jj < 8; ++jj)
      v8[jj] = (half_t)((vbuf[j0 + jj] - mean) * rstd * gs[gq * 64 + j0 + jj]);
    *(f16x8*)(xp + j0) = v8;
  }
}

// ---------------- fp16 MFMA GEMM: BK=32 ring-4, counted vmcnt (r16 proven) ----------------
__global__ __launch_bounds__(512) void gemm16r(const half_t* __restrict__ Xh,
                                               const half_t* __restrict__ Wh,
                                               half_t* __restrict__ Yh) {
  __shared__ __align__(16) char smem[65536];       // 4 ring slots / out tile
  const int tid = threadIdx.x;
  const int wave = tid >> 6, lane = tid & 63;
  const int lr = lane & 15, lq = lane >> 4;
  const int b = blockIdx.z;
  const int pix0 = blockIdx.x * 128;
  const int m0 = blockIdx.y * 128;
  const int wm = wave >> 1, wn = wave & 1;         // 4 m-waves x 2 px-waves

  const half_t* xb = Xh + ((size_t)b * HW + pix0) * 256;
  const half_t* wb = Wh + (size_t)m0 * 256;

  f32x4 acc[2][4];
#pragma unroll
  for (int i = 0; i < 2; ++i)
#pragma unroll
    for (int j = 0; j < 4; ++j) { f32x4 z = {0.f, 0.f, 0.f, 0.f}; acc[i][j] = z; }

#define STAGE(kt, s) do {                                                       \
    int r_ = tid >> 2, c_ = tid & 3;                                            \
    int cs_ = c_ ^ ((r_ >> 1) & 3);                                             \
    gload_lds16(xb + (size_t)r_ * 256 + (kt) * 32 + (cs_ << 3),                 \
                (half_t*)(smem + (s) * 16384) + tid * 8);                       \
    gload_lds16(wb + (size_t)r_ * 256 + (kt) * 32 + (cs_ << 3),                 \
                (half_t*)(smem + (s) * 16384 + 8192) + tid * 8);                \
  } while (0)

  STAGE(0, 0);
  STAGE(1, 1);

#pragma unroll
  for (int t = 0; t < 8; ++t) {
    if (t < 6) STAGE(t + 2, (t + 2) & 3);
    if (t < 6)       asm volatile("s_waitcnt vmcnt(4)" ::: "memory");
    else if (t == 6) asm volatile("s_waitcnt vmcnt(2)" ::: "memory");
    else             asm volatile("s_waitcnt vmcnt(0)" ::: "memory");
    __builtin_amdgcn_sched_barrier(0);
    __builtin_amdgcn_s_barrier();                  // all waves: tile t landed
    const char* slot = smem + (t & 3) * 16384;
    f16x8 afr[2], bfr[4];
#pragma unroll
    for (int mf = 0; mf < 2; ++mf) {
      int r = wm * 32 + mf * 16 + lr;
      afr[mf] = *(const f16x8*)(slot + 8192 + r * 64 + ((lq ^ ((r >> 1) & 3)) << 4));
    }
#pragma unroll
    for (int nf = 0; nf < 4; ++nf) {
      int r = wn * 64 + nf * 16 + lr;
      bfr[nf] = *(const f16x8*)(slot + r * 64 + ((lq ^ ((r >> 1) & 3)) << 4));
    }
#pragma unroll
    for (int mf = 0; mf < 2; ++mf)
#pragma unroll
      for (int nf = 0; nf < 4; ++nf)
        acc[mf][nf] = __builtin_amdgcn_mfma_f32_16x16x32_f16(afr[mf], bfr[nf], acc[mf][nf], 0, 0, 0);
  }
#undef STAGE
  asm volatile("s_waitcnt lgkmcnt(0)" ::: "memory");
  __builtin_amdgcn_sched_barrier(0);
  __builtin_amdgcn_s_barrier();                    // smem free for out tile

  // epilogue via swizzled LDS tile -> 256B row bursts
#pragma unroll
  for (int mf = 0; mf < 2; ++mf)
#pragma unroll
    for (int nf = 0; nf < 4; ++nf)
#pragma unroll
      for (int j = 0; j < 4; ++j) {
        int row = wm * 32 + mf * 16 + lq * 4 + j;
        int col = wn * 64 + nf * 16 + lr;
        int byte = row * 256 + ((col * 2) ^ ((row & 7) << 4));
        *(half_t*)(smem + byte) = (half_t)acc[mf][nf][j];
      }
  __syncthreads();
  half_t* dst_base = Yh + (size_t)(m0 >> 8) * ((size_t)B * C * HW)
                     + ((size_t)(b * C + (m0 & 255))) * HW + pix0;
#pragma unroll
  for (int it = 0; it < 4; ++it) {
    int i = it * 512 + tid;                 // 2048 chunks = 128 rows x 16
    int row = i >> 4, ch = i & 15;
    int src = row * 256 + ((ch * 16) ^ ((row & 7) << 4));
    *(f16x8*)(dst_base + (size_t)row * HW + ch * 8) = *(const f16x8*)(smem + src);
  }
}

// ---------------- fused depthwise 3x3 (alignbit + shfl halos) for Q, K(exp+sum), V ----------------
// grid (Hh/16, 3*C, B); block 256 = 16 rows x 16 col-groups. Branch is block-uniform.
__global__ __launch_bounds__(256) void dw3x3_all(const half_t* __restrict__ Yh,
                                                 const float* __restrict__ wq2,
                                                 const float* __restrict__ wk2,
                                                 const float* __restrict__ wv2,
                                                 half_t* __restrict__ Qh,
                                                 half_t* __restrict__ EK,
                                                 half_t* __restrict__ Vh,
                                                 float* __restrict__ Sk) {
  const size_t SZ = (size_t)B * C * HW;
  int ch = blockIdx.y;
  int ten = ch >> 8;                 // 0=Q, 1=K, 2=V
  int c = ch & 255;
  int b = blockIdx.z;
  int r = threadIdx.x >> 4;
  int cg = threadIdx.x & 15;         // col group (8 px)
  int lane = threadIdx.x & 63;
  int j0 = cg * 8;
  int i = blockIdx.x * 16 + r;
  const half_t* plane = Yh + (size_t)ten * SZ + ((size_t)(b * C + c)) * HW;
  const float* W2 = (ten == 0) ? wq2 : (ten == 1) ? wk2 : wv2;
  half_t wh[9];
#pragma unroll
  for (int k = 0; k < 9; ++k) wh[k] = (half_t)W2[c * 9 + k];
  const int lm1 = (lane - 1) & 63, lp1 = (lane + 1) & 63;
  f16x8 acc8 = {0, 0, 0, 0, 0, 0, 0, 0};
#pragma unroll
  for (int dr = 0; dr < 3; ++dr) {
    int ii = i + dr - 1;
    if (ii < 0 || ii >= Hh) continue;
    uint4 d = *(const uint4*)(plane + ii * Wd + j0);
    unsigned haloL = (unsigned)__shfl((int)d.w, lm1);   // prev lane's d3 (h7 in hi16)
    unsigned haloR = (unsigned)__shfl((int)d.x, lp1);   // next lane's d0 (h8 in lo16)
    if (cg == 0)  haloL = 0;                            // image left edge (SAME pad)
    if (cg == 15) haloR = 0;                            // image right edge
    unsigned m0 = __builtin_amdgcn_alignbit(d.x, haloL, 16);  // {h-1,h0}
    unsigned m1 = __builtin_amdgcn_alignbit(d.y, d.x, 16);    // {h1,h2}
    unsigned m2 = __builtin_amdgcn_alignbit(d.z, d.y, 16);    // {h3,h4}
    unsigned m3 = __builtin_amdgcn_alignbit(d.w, d.z, 16);    // {h5,h6}
    unsigned m4 = __builtin_amdgcn_alignbit(haloR, d.w, 16);  // {h7,h8}
    uint4 lshu = {m0, m1, m2, m3};
    uint4 rshu = {m1, m2, m3, m4};
    f16x8 cv  = __builtin_bit_cast(f16x8, d);
    f16x8 lsh = __builtin_bit_cast(f16x8, lshu);
    f16x8 rsh = __builtin_bit_cast(f16x8, rshu);
    acc8 += lsh * wh[dr * 3] + cv * wh[dr * 3 + 1] + rsh * wh[dr * 3 + 2];
  }
  size_t off = ((size_t)(b * C + c)) * HW + i * Wd + j0;
  if (ten == 1) {                    // K: exp + channel sum (fp32 exp)
    f16x8 o8;
    float local = 0.f;
#pragma unroll
    for (int p = 0; p < 8; ++p) {
      float e = expf((float)acc8[p]);  // logits ~N(0,small): no max pass needed
      o8[p] = (half_t)e;
      local += e;
    }
    *(f16x8*)(EK + off) = o8;
    __shared__ float red[256];
    int t = threadIdx.x;
    red[t] = local; __syncthreads();
    for (int st = 128; st > 0; st >>= 1) {
      if (t < st) red[t] += red[t + st];
      __syncthreads();
    }
    if (t == 0) atomicAdd(&Sk[b * C + c], red[0]);
  } else {
    half_t* dst = (ten == 0) ? Qh : Vh;
    *(f16x8*)(dst + off) = acc8;
  }
}

// ---------------- ctx_raw = EK @ V^T per head, pure MFMA ----------------
__global__ __launch_bounds__(256) void ctx_mfma(const half_t* __restrict__ EK,
                                                const half_t* __restrict__ V,
                                                float* __restrict__ part) {
  int bh = blockIdx.x, sp = blockIdx.y;
  int wave = threadIdx.x >> 6, lane = threadIdx.x & 63;
  int lr = lane & 15, lq = lane >> 4;
  const size_t base = (size_t)bh * HD * HW;
  const half_t* ekp = EK + base + (size_t)lr * HW;
  const half_t* vp  = V  + base + (size_t)lr * HW;
  f32x4 a00 = {0.f,0.f,0.f,0.f}, a01 = a00, a10 = a00, a11 = a00;
  const int n0w = sp * 1024 + wave * 256 + lq * 8;
#pragma unroll
  for (int ks = 0; ks < 8; ++ks) {
    int n = n0w + ks * 32;
    f16x8 fa0 = *(const f16x8*)(ekp + n);
    f16x8 fa1 = *(const f16x8*)(ekp + (size_t)16 * HW + n);
    f16x8 fb0 = *(const f16x8*)(vp + n);
    f16x8 fb1 = *(const f16x8*)(vp + (size_t)16 * HW + n);
    a00 = __builtin_amdgcn_mfma_f32_16x16x32_f16(fa0, fb0, a00, 0, 0, 0);
    a01 = __builtin_amdgcn_mfma_f32_16x16x32_f16(fa0, fb1, a01, 0, 0, 0);
    a10 = __builtin_amdgcn_mfma_f32_16x16x32_f16(fa1, fb0, a10, 0, 0, 0);
    a11 = __builtin_amdgcn_mfma_f32_16x16x32_f16(fa1, fb1, a11, 0, 0, 0);
  }
  __shared__ float red[4][1024];
#pragma unroll
  for (int j = 0; j < 4; ++j) {
    int dlo = lq * 4 + j;
    red[wave][(dlo)      * 32 + lr]      = a00[j];
    red[wave][(dlo)      * 32 + 16 + lr] = a01[j];
    red[wave][(dlo + 16) * 32 + lr]      = a10[j];
    red[wave][(dlo + 16) * 32 + 16 + lr] = a11[j];
  }
  __syncthreads();
  float* pp = part + ((size_t)sp * 32 + bh) * 1024;
  for (int idx = threadIdx.x; idx < 1024; idx += 256)
    pp[idx] = red[0][idx] + red[1][idx] + red[2][idx] + red[3][idx];
}

// ---------------- reduce ctx partials, apply 1/S, emit fp16 TRANSPOSED [e][d] ----------------
__global__ __launch_bounds__(256) void ctxred(const float* __restrict__ part,
                                              const float* __restrict__ Sk,
                                              half_t* __restrict__ ctxh) {
  int bh = blockIdx.x;
  int t = threadIdx.x;
  for (int idx = t; idx < 1024; idx += 256) {
    int d = idx >> 5, e = idx & 31;
    float s = 0.f;
#pragma unroll
    for (int sp = 0; sp < NSP; ++sp) s += part[((size_t)sp * 32 + bh) * 1024 + idx];
    ctxh[(size_t)bh * 1024 + e * 32 + d] = (half_t)(s / Sk[bh * HD + d]);
  }
}

// ---------------- attn6b: P@ctx (MFMA) -> SiLU -> LDS O tile -> O@Wout^T -> fp32 out ----------------
__global__ __launch_bounds__(256) void attn6b(const half_t* __restrict__ Qh,
                                              const half_t* __restrict__ ctxh,
                                              const half_t* __restrict__ Woh,
                                              float* __restrict__ outp) {
  const int b = blockIdx.y;
  const int lane = threadIdx.x & 63;
  const int w = threadIdx.x >> 6;
  const int lr = lane & 15, lq = lane >> 4;
  const int px0 = blockIdx.x * 64;
  const int px = px0 + w * 16 + lr;                   // phase-1 A-row pixel
  __shared__ __align__(16) char osm[64 * 512];        // 32KB O tile [px][c] fp16 swizzled

  // ---- phase 1: O = silu(softmax(q) @ ctx) * OSCALE ----
  {
    const int pxl_base = w * 16 + lq * 4;
    const half_t* cb = ctxh + ((size_t)b * HEADS) * 1024;
    f16x8 cf0 = *(const f16x8*)(cb + (lr)      * 32 + lq * 8);
    f16x8 cf1 = *(const f16x8*)(cb + (16 + lr) * 32 + lq * 8);
#pragma unroll
    for (int h = 0; h < HEADS; ++h) {
      f16x8 nf0, nf1;
      if (h < HEADS - 1) {                            // prefetch next head's frags
        const half_t* nb = cb + (size_t)(h + 1) * 1024;
        nf0 = *(const f16x8*)(nb + (lr)      * 32 + lq * 8);
        nf1 = *(const f16x8*)(nb + (16 + lr) * 32 + lq * 8);
      }
      const half_t* qp = Qh + ((size_t)(b * C + h * HD + lq * 8)) * HW + px;
      float ev[8];
      float psum = 0.f;
#pragma unroll
      for (int j = 0; j < 8; ++j) {
        ev[j] = expf((float)qp[(size_t)j * HW]);      // no max pass: logits bounded
        psum += ev[j];
      }
      float s = psum;
      s += __shfl_xor(s, 16, 64);
      s += __shfl_xor(s, 32, 64);
      float inv = 0.1767766952966369f / s;            // 32^-0.5 / s
      f16x8 pa;
#pragma unroll
      for (int j = 0; j < 8; ++j) pa[j] = (half_t)(ev[j] * inv);

      f32x4 z = {0.f, 0.f, 0.f, 0.f};
      f32x4 a0 = __builtin_amdgcn_mfma_f32_16x16x32_f16(pa, cf0, z, 0, 0, 0);
      f32x4 a1 = __builtin_amdgcn_mfma_f32_16x16x32_f16(pa, cf1, z, 0, 0, 0);
#pragma unroll
      for (int eh = 0; eh < 2; ++eh) {
        f32x4 a = eh ? a1 : a0;
        int cc = h * 32 + eh * 16 + lr;
#pragma unroll
        for (int j = 0; j < 4; ++j) {
          int pxl = pxl_base + j;
          float v = a[j];
          float sg = 1.f / (1.f + expf(-v));
          int byte = pxl * 512 + ((cc * 2) ^ ((pxl & 7) << 4));
          *(half_t*)(osm + byte) = (half_t)(v * sg * OSCALE);
        }
      }
      cf0 = nf0; cf1 = nf1;
    }
  }
  __syncthreads();

  // ---- phase 2: out = O @ Woh^T / OSCALE ----
  f32x4 acc[4][4];
#pragma unroll
  for (int i = 0; i < 4; ++i)
#pragma unroll
    for (int j = 0; j < 4; ++j) { f32x4 z = {0.f, 0.f, 0.f, 0.f}; acc[i][j] = z; }

  const half_t* wbase = Woh + ((size_t)(w * 64 + lr)) * 256 + lq * 8;
#pragma unroll
  for (int k0 = 0; k0 < 256; k0 += 32) {
    f16x8 afr[4], bfr[4];
#pragma unroll
    for (int mf = 0; mf < 4; ++mf)
      afr[mf] = *(const f16x8*)(wbase + (size_t)(mf * 16) * 256 + k0);
#pragma unroll
    for (int nf = 0; nf < 4; ++nf) {
      int r = nf * 16 + lr;
      bfr[nf] = *(const f16x8*)(osm + r * 512 + ((k0 * 2 + lq * 16) ^ ((r & 7) << 4)));
    }
#pragma unroll
    for (int mf = 0; mf < 4; ++mf)
#pragma unroll
      for (int nf = 0; nf < 4; ++nf)
        acc[mf][nf] = __builtin_amdgcn_mfma_f32_16x16x32_f16(afr[mf], bfr[nf], acc[mf][nf], 0, 0, 0);
  }

  // D[row=oc][col=px]; fp32 stores, 16 lanes consecutive px = 64B segments
#pragma unroll
  for (int mf = 0; mf < 4; ++mf) {
    int oc = w * 64 + mf * 16 + lq * 4;
#pragma unroll
    for (int nf = 0; nf < 4; ++nf) {
      float* dst = outp + ((size_t)(b * C + oc)) * HW + px0 + nf * 16 + lr;
#pragma unroll
      for (int j = 0; j < 4; ++j)
        dst[(size_t)j * HW] = acc[mf][nf][j] * (1.0f / OSCALE);
    }
  }
}

extern "C" void kernel_launch(void* const* d_in, const int* in_sizes, int n_in,
                              void* d_out, int out_size, void* d_ws, size_t ws_size,
                              hipStream_t stream) {
  const float* fmap = (const float*)d_in[0];
  const float* g    = (const float*)d_in[1];
  const float* wq1  = (const float*)d_in[2];
  const float* wq2  = (const float*)d_in[3];
  const float* wk1  = (const float*)d_in[4];
  const float* wk2  = (const float*)d_in[5];
  const float* wv1  = (const float*)d_in[6];
  const float* wv2  = (const float*)d_in[7];
  const float* wout = (const float*)d_in[8];
  float* out = (float*)d_out;
  char* ws = (char*)d_ws;

  const size_t SZ = (size_t)B * C * HW;
  const size_t Mi = (size_t)1 << 20;
  // layout (byte offsets), live ranges audited:
  half_t* Xh   = (half_t*)(ws);                  // [0,32Mi)    ln2 -> gemm
  half_t* Yh   = (half_t*)(ws + 32 * Mi);        // [32,128Mi)  Yq|Yk|Yv fp16
  half_t* Qh   = (half_t*)(ws + 128 * Mi);       // [128,160Mi) dw -> attn6b
  half_t* EK   = (half_t*)(ws);                  // [0,32Mi)    exp(k) fp16 (Xh dead)
  half_t* Vh   = (half_t*)out;                   // d_out as fp16 V until attn6b overwrites
  float*  part = (float*)(ws + 96 * Mi);         // [96,98Mi)   over dead Yv (full overwrite)
  float*  Sk   = (float*)(ws + 160 * Mi);        // 4KB — outside all tensor regions
  half_t* ctxh = (half_t*)(ws + 100 * Mi);       // 64KB over dead Yv (full overwrite)
  half_t* Wh   = (half_t*)(ws + 192 * Mi);
  half_t* Woh  = (half_t*)(ws + 192 * Mi + 512 * 1024);

  wcvt_all<<<dim3(1024), 256, 0, stream>>>(wq1, wk1, wv1, wout, Wh, Woh, Sk);

  ln2<<<dim3(HW / 64, B), 256, 0, stream>>>(fmap, g, Xh);

  gemm16r<<<dim3(HW / 128, 6, B), 512, 0, stream>>>(Xh, Wh, Yh);

  dw3x3_all<<<dim3(Hh / 16, 3 * C, B), 256, 0, stream>>>(Yh, wq2, wk2, wv2,
                                                         Qh, EK, Vh, Sk);

  ctx_mfma<<<dim3(HEADS * B, NSP), 256, 0, stream>>>(EK, Vh, part);
  ctxred<<<dim3(32), 256, 0, stream>>>(part, Sk, ctxh);

  attn6b<<<dim3(HW / 64, B), 256, 0, stream>>>(Qh, ctxh, Woh, out);
}